// Round 7
// baseline (315.036 us; speedup 1.0000x reference)
//
#include <hip/hip_runtime.h>
#include <hip/hip_bf16.h>

// Problem: B=2, S=2048, E=1024, H=16, D=64. All inputs fp32, output fp32.
// Pipeline: cvt X->bf16 | transpose W->bf16 [N][K] | fused QKV GEMM (grid.z=3)
//           -> Q(scaled log2e/8),K [BH][S][D], V^T [BH][D][S]
//           | flash attention (NO K/V LDS staging: MFMA fragments loaded
//           directly from global -- K/V are L2-resident per XCD (2MB/4MB);
//           swapped QK^T, exp2 softmax, defer-max T13, cvt_pk T12; only LDS
//           use is the per-wave P buffer) | GEMM -> fp32 + bo.
// GEMM LDS tiles: T2 XOR swizzle byte ^= ((row&7)<<4), staged via
// global_load_lds with inverse-swizzled global source (linear LDS dest).
// History: r3 dbuf+counted-vmcnt raced (1e-2) -> full-drain only; r6 LDS-cost
// model: staged attn moved ~3.1GB through LDS (~45us) -> dropped staging
// (m169 lesson: don't stage what L2 already holds).

#define EMBED 1024
#define NHEAD 16
#define HDIM 64
#define SEQ 2048
#define MROWS 4096  // B*S

typedef __attribute__((ext_vector_type(8))) __bf16 bf16x8;
typedef __attribute__((ext_vector_type(4))) float f32x4;

__device__ __forceinline__ unsigned short f2bf(float f) {
  unsigned int u = __builtin_bit_cast(unsigned int, f);
  u += 0x7fffu + ((u >> 16) & 1u);  // round-to-nearest-even
  return (unsigned short)(u >> 16);
}

// packed f32x2 -> bf16x2 (T12 recipe; no builtin on gfx950)
__device__ __forceinline__ int cvtpk_bf16(float lo, float hi) {
  int r;
  asm("v_cvt_pk_bf16_f32 %0, %1, %2" : "=v"(r) : "v"(lo), "v"(hi));
  return r;
}

// swizzled byte offset within a [rows][128B] LDS tile
__device__ __forceinline__ int swz(int row, int bcol) {
  return row * 128 + (bcol ^ ((row & 7) << 4));
}

// async global->LDS, 16B per lane. LDS dest = base + lane*16 (linear).
__device__ __forceinline__ void gload16(const void* g, void* l) {
  __builtin_amdgcn_global_load_lds((const __attribute__((address_space(1))) void*)g,
                                   (__attribute__((address_space(3))) void*)l, 16, 0, 0);
}

// ---- fp32 -> bf16, 8 elements/thread; blockIdx.y selects src/dst ----
__global__ __launch_bounds__(256) void cvt_f32_bf16(const float* __restrict__ i0, const float* __restrict__ i1,
                                                    const float* __restrict__ i2,
                                                    unsigned short* __restrict__ o0, unsigned short* __restrict__ o1,
                                                    unsigned short* __restrict__ o2) {
  const float* in; unsigned short* out;
  switch (blockIdx.y) {
    case 0: in = i0; out = o0; break;
    case 1: in = i1; out = o1; break;
    default: in = i2; out = o2; break;
  }
  int i = blockIdx.x * 256 + threadIdx.x;
  const float4* p = reinterpret_cast<const float4*>(in) + (size_t)i * 2;
  float4 a = p[0], b = p[1];
  int4 r;
  r.x = cvtpk_bf16(a.x, a.y);
  r.y = cvtpk_bf16(a.z, a.w);
  r.z = cvtpk_bf16(b.x, b.y);
  r.w = cvtpk_bf16(b.z, b.w);
  reinterpret_cast<int4*>(out)[i] = r;
}

// ---- W [K][N] fp32 -> Wt [N][K] bf16, 64x64 LDS tiles ----
__global__ __launch_bounds__(256) void wtrans(const float* __restrict__ w0, const float* __restrict__ w1,
                                              const float* __restrict__ w2, const float* __restrict__ w3,
                                              unsigned short* __restrict__ o0, unsigned short* __restrict__ o1,
                                              unsigned short* __restrict__ o2, unsigned short* __restrict__ o3) {
  __shared__ float tile[64][65];
  const float* src; unsigned short* dst;
  switch (blockIdx.z) {
    case 0: src = w0; dst = o0; break;
    case 1: src = w1; dst = o1; break;
    case 2: src = w2; dst = o2; break;
    default: src = w3; dst = o3; break;
  }
  const int k0 = blockIdx.y * 64, n0 = blockIdx.x * 64;
  const int c = threadIdx.x & 63, r0 = threadIdx.x >> 6;
#pragma unroll
  for (int i = 0; i < 16; ++i) {
    int r = r0 + i * 4;
    tile[r][c] = src[(size_t)(k0 + r) * EMBED + n0 + c];
  }
  __syncthreads();
#pragma unroll
  for (int i = 0; i < 16; ++i) {
    int nr = r0 + i * 4;
    dst[(size_t)(n0 + nr) * EMBED + k0 + c] = f2bf(tile[c][nr]);
  }
}

// ---- shared GEMM core: C[128x128 tile] = A @ Bt^T + bias, then *oscale ----
// A bf16 [M][K]; Bt bf16 [N][K]. Staging via global_load_lds (m97 pattern).
// mode 0: bf16 scatter to [B*H][S][D]; mode 1: fp32 row-major;
// mode 2: bf16 V^T scatter to [B*H][D][S], 4 s-packed per 8B store.
__device__ __forceinline__ void gemm_core(const unsigned short* __restrict__ A,
                                          const unsigned short* __restrict__ Bt,
                                          const float* __restrict__ bias,
                                          void* __restrict__ C, float oscale, int mode) {
  constexpr int K = EMBED;
  __shared__ __align__(16) unsigned short Alds[128 * 64];
  __shared__ __align__(16) unsigned short Blds[128 * 64];
  char* Ab8 = (char*)Alds; char* Bb8 = (char*)Blds;
  const char* AB = (const char*)A;
  const char* BB = (const char*)Bt;
  const int tid = threadIdx.x;
  const int lane = tid & 63, w = tid >> 6;
  const int wr = w >> 1, wc = w & 1;
  const int fr = lane & 15, fq = lane >> 4;
  const int m0 = blockIdx.y * 128, n0 = blockIdx.x * 128;
  const int bcol = (lane & 7) * 16;

  f32x4 acc[4][4];
#pragma unroll
  for (int m = 0; m < 4; ++m)
#pragma unroll
    for (int n = 0; n < 4; ++n) acc[m][n] = f32x4{0.f, 0.f, 0.f, 0.f};

  for (int k0 = 0; k0 < K; k0 += 64) {
    __syncthreads();
#pragma unroll
    for (int i = 0; i < 4; ++i) {
      int row = w * 32 + i * 8 + (lane >> 3);
      int sc_ = bcol ^ ((row & 7) << 4);
      gload16(AB + (size_t)(m0 + row) * (K * 2) + k0 * 2 + sc_, Ab8 + w * 4096 + i * 1024);
      gload16(BB + (size_t)(n0 + row) * (K * 2) + k0 * 2 + sc_, Bb8 + w * 4096 + i * 1024);
    }
    __syncthreads();  // drains vmcnt(0) -> tile staged
#pragma unroll
    for (int ks = 0; ks < 2; ++ks) {
      bf16x8 af[4], bfr[4];
#pragma unroll
      for (int m = 0; m < 4; ++m) {
        int ar = wr * 64 + m * 16 + fr;
        af[m] = *reinterpret_cast<const bf16x8*>(Ab8 + swz(ar, ks * 64 + fq * 16));
      }
#pragma unroll
      for (int n = 0; n < 4; ++n) {
        int br = wc * 64 + n * 16 + fr;
        bfr[n] = *reinterpret_cast<const bf16x8*>(Bb8 + swz(br, ks * 64 + fq * 16));
      }
#pragma unroll
      for (int m = 0; m < 4; ++m)
#pragma unroll
        for (int n = 0; n < 4; ++n)
          acc[m][n] = __builtin_amdgcn_mfma_f32_16x16x32_bf16(af[m], bfr[n], acc[m][n], 0, 0, 0);
    }
  }

#pragma unroll
  for (int n = 0; n < 4; ++n) {
    int col = n0 + wc * 64 + n * 16 + fr;
    float bv = bias[col];
#pragma unroll
    for (int m = 0; m < 4; ++m) {
      int rowb = m0 + wr * 64 + m * 16 + fq * 4;
      if (mode == 2) {
        int b = rowb >> 11, s0 = rowb & (SEQ - 1);
        int h = col >> 6, d = col & 63;
        int2 pk;
        pk.x = cvtpk_bf16((acc[m][n][0] + bv) * oscale, (acc[m][n][1] + bv) * oscale);
        pk.y = cvtpk_bf16((acc[m][n][2] + bv) * oscale, (acc[m][n][3] + bv) * oscale);
        *reinterpret_cast<int2*>(
            &reinterpret_cast<unsigned short*>(C)[((size_t)((b * NHEAD + h) * HDIM + d)) * SEQ + s0]) = pk;
      } else if (mode == 0) {
#pragma unroll
        for (int r = 0; r < 4; ++r) {
          int row = rowb + r;
          float v = (acc[m][n][r] + bv) * oscale;
          int b = row >> 11, s = row & (SEQ - 1), h = col >> 6, d = col & 63;
          reinterpret_cast<unsigned short*>(C)[((size_t)((b * NHEAD + h) * SEQ + s) << 6) + d] = f2bf(v);
        }
      } else {
#pragma unroll
        for (int r = 0; r < 4; ++r)
          reinterpret_cast<float*>(C)[(size_t)(rowb + r) * EMBED + col] = acc[m][n][r] + bv;
      }
    }
  }
}

// fused QKV projection: blockIdx.z picks {Q, K, V}; 768 blocks = 3/CU.
__global__ __launch_bounds__(256) void gemm_qkv(
    const unsigned short* __restrict__ Xq, const unsigned short* __restrict__ Xk,
    const unsigned short* __restrict__ Xv,
    const unsigned short* __restrict__ Wqt, const unsigned short* __restrict__ Wkt,
    const unsigned short* __restrict__ Wvt,
    const float* __restrict__ bq, const float* __restrict__ bk, const float* __restrict__ bv,
    unsigned short* __restrict__ Qb, unsigned short* __restrict__ Kb,
    unsigned short* __restrict__ Vtb, float qscale) {
  switch (blockIdx.z) {
    case 0: gemm_core(Xq, Wqt, bq, Qb, qscale, 0); break;
    case 1: gemm_core(Xk, Wkt, bk, Kb, 1.0f, 0); break;
    default: gemm_core(Xv, Wvt, bv, Vtb, 1.0f, 2); break;
  }
}

__global__ __launch_bounds__(256) void gemm_out(const unsigned short* __restrict__ A,
                                                const unsigned short* __restrict__ Bt,
                                                const float* __restrict__ bias,
                                                float* __restrict__ C) {
  gemm_core(A, Bt, bias, C, 1.0f, 1);
}

// ---- flash attention, zero-staging ----
// Q,K bf16 [B*H][S][D] (Q pre-scaled by log2e/8); Vt bf16 [B*H][D][S].
// MFMA fragments read DIRECTLY from global (L1/L2-resident: XCD swizzle keeps
// each XCD's K/V working set at 2MB < 4MB L2; all 4 waves share each 16KB
// tile -> L1 hits). Swapped QK^T: sc = mfma(K,Q) -> S^T, 64 k-scores for
// q=fr in-lane. Only LDS: per-wave P buffer (same-wave write->read).
// One plain __syncthreads per tile keeps waves in phase for L1 locality
// (all loads consumed before it -> its drain is free).
__global__ __launch_bounds__(256) void attn(const unsigned short* __restrict__ Q,
                                            const unsigned short* __restrict__ Kk,
                                            const unsigned short* __restrict__ Vt,
                                            unsigned short* __restrict__ AO) {
  __shared__ __align__(16) unsigned short Plds[4][16 * 64];
  const int tid = threadIdx.x, lane = tid & 63, w = tid >> 6;
  const int fr = lane & 15, fq = lane >> 4;
  char* Pb8 = (char*)&Plds[w][0];

  // XCD swizzle: all 32 q-blocks of a head on one XCD (round-robin lin%8).
  const int lin = blockIdx.x;
  const int head = (lin & 7) * 4 + ((lin >> 3) & 3);
  const int q0 = (lin >> 5) * 64;
  const size_t hb = (size_t)head * SEQ * HDIM;
  const unsigned short* Qh = Q + hb;
  const unsigned short* Kh = Kk + hb;
  const unsigned short* Vh = Vt + hb;  // [d][s]

  bf16x8 qf[2];
  {
    size_t qoff = (size_t)(q0 + w * 16 + fr) * HDIM + fq * 8;
    qf[0] = *reinterpret_cast<const bf16x8*>(&Qh[qoff]);
    qf[1] = *reinterpret_cast<const bf16x8*>(&Qh[qoff + 32]);
  }
  f32x4 oacc[4];
#pragma unroll
  for (int n = 0; n < 4; ++n) oacc[n] = f32x4{0.f, 0.f, 0.f, 0.f};
  float mrow = -1e30f, lrow = 0.f;
  const int rsrc = (fq << 4) + (fq << 2);  // lane fq*16 + fq*4 (+rr): stats for q=fq*4+rr

  // fragment base pointers (per-lane, loop-invariant)
  const unsigned short* Kf = Kh + (size_t)fr * HDIM + fq * 8;      // + (kt*64+n*16)*64
  const unsigned short* Vf = Vh + (size_t)fr * SEQ + fq * 8;       // + n*16*SEQ + kt*64 (+32)

  for (int kt = 0; kt < SEQ / 64; ++kt) {
    // S^T = K·Q^T: sc[n] rows k = n*16+fq*4+r, col q = fr (log2 domain)
    f32x4 sc[4];
#pragma unroll
    for (int n = 0; n < 4; ++n) {
      const unsigned short* kp = Kf + (size_t)(kt * 64 + n * 16) * HDIM;
      bf16x8 k0 = *reinterpret_cast<const bf16x8*>(kp);
      bf16x8 k1 = *reinterpret_cast<const bf16x8*>(kp + 32);
      f32x4 a = f32x4{0.f, 0.f, 0.f, 0.f};
      a = __builtin_amdgcn_mfma_f32_16x16x32_bf16(k0, qf[0], a, 0, 0, 0);
      a = __builtin_amdgcn_mfma_f32_16x16x32_bf16(k1, qf[1], a, 0, 0, 0);
      sc[n] = a;
    }

    // tile max for this lane's q (=fr): in-lane tree (max3-friendly) + 2 shfl
    float mx0 = fmaxf(fmaxf(sc[0][0], sc[0][1]), fmaxf(sc[0][2], sc[0][3]));
    float mx1 = fmaxf(fmaxf(sc[1][0], sc[1][1]), fmaxf(sc[1][2], sc[1][3]));
    float mx2 = fmaxf(fmaxf(sc[2][0], sc[2][1]), fmaxf(sc[2][2], sc[2][3]));
    float mx3 = fmaxf(fmaxf(sc[3][0], sc[3][1]), fmaxf(sc[3][2], sc[3][3]));
    float mt = fmaxf(fmaxf(mx0, mx1), fmaxf(mx2, mx3));
    mt = fmaxf(mt, __shfl_xor(mt, 16));
    mt = fmaxf(mt, __shfl_xor(mt, 32));

    // T13 defer-max: only rescale when some row's max grew past 2^8 headroom
    if (!__all(mt <= mrow + 8.0f)) {
      float mn = fmaxf(mrow, mt);
      float resc = exp2f(mrow - mn);
      lrow *= resc;
      float rq[4];
#pragma unroll
      for (int rr = 0; rr < 4; ++rr) rq[rr] = __shfl(resc, rsrc + rr, 64);
#pragma unroll
      for (int n = 0; n < 4; ++n)
#pragma unroll
        for (int rr = 0; rr < 4; ++rr) oacc[n][rr] *= rq[rr];
      mrow = mn;
    }

    float p[4][4];
    float ps = 0.f;
#pragma unroll
    for (int n = 0; n < 4; ++n)
#pragma unroll
      for (int r = 0; r < 4; ++r) {
        p[n][r] = exp2f(sc[n][r] - mrow);
        ps += p[n][r];
      }
    ps += __shfl_xor(ps, 16);
    ps += __shfl_xor(ps, 32);
    lrow += ps;

    // P -> Plds[q=fr][k] (swizzled), 4x ds_write_b64 via cvt_pk; k = n*16+fq*4+r
#pragma unroll
    for (int n = 0; n < 4; ++n) {
      int2 pk;
      pk.x = cvtpk_bf16(p[n][0], p[n][1]);
      pk.y = cvtpk_bf16(p[n][2], p[n][3]);
      *reinterpret_cast<int2*>(Pb8 + swz(fr, n * 32 + fq * 8)) = pk;
    }

    bf16x8 pa0 = *reinterpret_cast<const bf16x8*>(Pb8 + swz(fr, fq * 16));
    bf16x8 pa1 = *reinterpret_cast<const bf16x8*>(Pb8 + swz(fr, 64 + fq * 16));
#pragma unroll
    for (int n = 0; n < 4; ++n) {
      const unsigned short* vp = Vf + (size_t)(n * 16) * SEQ + kt * 64;
      bf16x8 vb0 = *reinterpret_cast<const bf16x8*>(vp);
      bf16x8 vb1 = *reinterpret_cast<const bf16x8*>(vp + 32);
      oacc[n] = __builtin_amdgcn_mfma_f32_16x16x32_bf16(pa0, vb0, oacc[n], 0, 0, 0);
      oacc[n] = __builtin_amdgcn_mfma_f32_16x16x32_bf16(pa1, vb1, oacc[n], 0, 0, 0);
    }

    __syncthreads();  // keep 4 waves in phase so the shared 16KB tile stays L1-hot
  }

  const int b = head >> 4, h = head & 15;
  float lr[4];
#pragma unroll
  for (int rr = 0; rr < 4; ++rr) lr[rr] = __shfl(lrow, rsrc + rr, 64);
#pragma unroll
  for (int rr = 0; rr < 4; ++rr) {
    float inv = 1.0f / lr[rr];
    int srow = q0 + w * 16 + fq * 4 + rr;
    size_t ob = (size_t)(b * SEQ + srow) * EMBED + h * 64;
#pragma unroll
    for (int n = 0; n < 4; ++n) AO[ob + n * 16 + fr] = f2bf(oacc[n][rr] * inv);
  }
}

extern "C" void kernel_launch(void* const* d_in, const int* in_sizes, int n_in,
                              void* d_out, int out_size, void* d_ws, size_t ws_size,
                              hipStream_t stream) {
  const float* q32 = (const float*)d_in[0];
  const float* k32 = (const float*)d_in[1];
  const float* v32 = (const float*)d_in[2];
  const float* Wq = (const float*)d_in[3]; const float* bq = (const float*)d_in[4];
  const float* Wk = (const float*)d_in[5]; const float* bk = (const float*)d_in[6];
  const float* Wv = (const float*)d_in[7]; const float* bv = (const float*)d_in[8];
  const float* Wo = (const float*)d_in[9]; const float* bo = (const float*)d_in[10];
  float* out = (float*)d_out;

  char* ws = (char*)d_ws;
  const size_t MB = 1u << 20;
  unsigned short* Xq  = (unsigned short*)(ws + 0 * MB);
  unsigned short* Xk  = (unsigned short*)(ws + 8 * MB);
  unsigned short* Xv  = (unsigned short*)(ws + 16 * MB);
  unsigned short* Wqt = (unsigned short*)(ws + 24 * MB);
  unsigned short* Wkt = (unsigned short*)(ws + 26 * MB);
  unsigned short* Wvt = (unsigned short*)(ws + 28 * MB);
  unsigned short* Wot = (unsigned short*)(ws + 30 * MB);
  unsigned short* Qb  = (unsigned short*)(ws + 32 * MB);
  unsigned short* Kb  = (unsigned short*)(ws + 40 * MB);
  unsigned short* Vtb = (unsigned short*)(ws + 48 * MB);
  unsigned short* AO  = Xq;  // safe: GEMM-Q (sole Xq reader) completes before attn writes

  const int n8 = (MROWS * EMBED) / 8;  // 524288
  cvt_f32_bf16<<<dim3(n8 / 256, 3), 256, 0, stream>>>(q32, k32, v32, Xq, Xk, Xv);
  wtrans<<<dim3(16, 16, 4), 256, 0, stream>>>(Wq, Wk, Wv, Wo, Wqt, Wkt, Wvt, Wot);

  const float qscale = 0.125f * 1.44269504088896340736f;  // (1/sqrt(64)) * log2(e)
  gemm_qkv<<<dim3(EMBED / 128, MROWS / 128, 3), 256, 0, stream>>>(
      Xq, Xk, Xv, Wqt, Wkt, Wvt, bq, bk, bv, Qb, Kb, Vtb, qscale);

  attn<<<dim3(SEQ / 64 * 32), 256, 0, stream>>>(Qb, Kb, Vtb, AO);

  gemm_out<<<dim3(EMBED / 128, MROWS / 128), 256, 0, stream>>>(AO, Wot, bo, out);
}

// Round 8
// 174.696 us; speedup vs baseline: 1.8033x; 1.8033x over previous
//
#include <hip/hip_runtime.h>
#include <hip/hip_bf16.h>

// Problem: B=2, S=2048, E=1024, H=16, D=64. All inputs fp32, output fp32.
// Pipeline: wtrans W->bf16 [N][K] | fused QKV GEMM (grid.z=3, A staged as f32
//           with in-staging cvt -> no separate cvt pass) -> Q(scaled log2e/8),
//           K [BH][S][D], V^T [BH][D][S] | flash attention (round-6 verified:
//           LDS-staged K/V, T14 reg-staged double buffer, swapped QK^T, exp2
//           softmax, defer-max T13, cvt_pk T12, one __syncthreads per tile)
//           | GEMM -> fp32 + bo.
// LDS tiles: T2 XOR swizzle byte ^= ((row&7)<<4) within 128B rows.
// History: r3 dbuf+counted-vmcnt raced (1e-2) -> full-drain only. r7 zero-
// staging attn was LATENCY-BOUND (MfmaUtil 5.8%, VALU 24%, 239us): MFMA
// operands must come from LDS with staging in front, not direct global ->
// reverted to r6 attn. r8: cvt fused into QKV A-staging (saves ~72MB HBM).

#define EMBED 1024
#define NHEAD 16
#define HDIM 64
#define SEQ 2048
#define MROWS 4096  // B*S

typedef __attribute__((ext_vector_type(8))) __bf16 bf16x8;
typedef __attribute__((ext_vector_type(4))) float f32x4;

__device__ __forceinline__ unsigned short f2bf(float f) {
  unsigned int u = __builtin_bit_cast(unsigned int, f);
  u += 0x7fffu + ((u >> 16) & 1u);  // round-to-nearest-even
  return (unsigned short)(u >> 16);
}

// packed f32x2 -> bf16x2 (T12 recipe; no builtin on gfx950)
__device__ __forceinline__ int cvtpk_bf16(float lo, float hi) {
  int r;
  asm("v_cvt_pk_bf16_f32 %0, %1, %2" : "=v"(r) : "v"(lo), "v"(hi));
  return r;
}

// swizzled byte offset within a [rows][128B] LDS tile
__device__ __forceinline__ int swz(int row, int bcol) {
  return row * 128 + (bcol ^ ((row & 7) << 4));
}

// async global->LDS, 16B per lane. LDS dest = base + lane*16 (linear).
__device__ __forceinline__ void gload16(const void* g, void* l) {
  __builtin_amdgcn_global_load_lds((const __attribute__((address_space(1))) void*)g,
                                   (__attribute__((address_space(3))) void*)l, 16, 0, 0);
}

// ---- W [K][N] fp32 -> Wt [N][K] bf16, 64x64 LDS tiles ----
__global__ __launch_bounds__(256) void wtrans(const float* __restrict__ w0, const float* __restrict__ w1,
                                              const float* __restrict__ w2, const float* __restrict__ w3,
                                              unsigned short* __restrict__ o0, unsigned short* __restrict__ o1,
                                              unsigned short* __restrict__ o2, unsigned short* __restrict__ o3) {
  __shared__ float tile[64][65];
  const float* src; unsigned short* dst;
  switch (blockIdx.z) {
    case 0: src = w0; dst = o0; break;
    case 1: src = w1; dst = o1; break;
    case 2: src = w2; dst = o2; break;
    default: src = w3; dst = o3; break;
  }
  const int k0 = blockIdx.y * 64, n0 = blockIdx.x * 64;
  const int c = threadIdx.x & 63, r0 = threadIdx.x >> 6;
#pragma unroll
  for (int i = 0; i < 16; ++i) {
    int r = r0 + i * 4;
    tile[r][c] = src[(size_t)(k0 + r) * EMBED + n0 + c];
  }
  __syncthreads();
#pragma unroll
  for (int i = 0; i < 16; ++i) {
    int nr = r0 + i * 4;
    dst[(size_t)(n0 + nr) * EMBED + k0 + c] = f2bf(tile[c][nr]);
  }
}

// ---- shared GEMM core: C[128x128 tile] = A @ Bt^T + bias, then *oscale ----
// AF32=true: A is fp32 [M][K], reg-staged with in-flight cvt_pk -> swizzled
// ds_write (fuses the x->bf16 pass into the GEMM). AF32=false: A bf16 [M][K]
// staged via global_load_lds (m97 pattern). Bt always bf16 [N][K] via
// global_load_lds. mode 0: bf16 scatter to [B*H][S][D]; mode 1: fp32
// row-major; mode 2: bf16 V^T scatter to [B*H][D][S].
template <bool AF32>
__device__ __forceinline__ void gemm_core(const void* __restrict__ A,
                                          const unsigned short* __restrict__ Bt,
                                          const float* __restrict__ bias,
                                          void* __restrict__ C, float oscale, int mode) {
  constexpr int K = EMBED;
  __shared__ __align__(16) unsigned short Alds[128 * 64];
  __shared__ __align__(16) unsigned short Blds[128 * 64];
  char* Ab8 = (char*)Alds; char* Bb8 = (char*)Blds;
  const char* AB = (const char*)A;
  const char* BB = (const char*)Bt;
  const int tid = threadIdx.x;
  const int lane = tid & 63, w = tid >> 6;
  const int wr = w >> 1, wc = w & 1;
  const int fr = lane & 15, fq = lane >> 4;
  const int m0 = blockIdx.y * 128, n0 = blockIdx.x * 128;
  const int bcol = (lane & 7) * 16;

  f32x4 acc[4][4];
#pragma unroll
  for (int m = 0; m < 4; ++m)
#pragma unroll
    for (int n = 0; n < 4; ++n) acc[m][n] = f32x4{0.f, 0.f, 0.f, 0.f};

  for (int k0 = 0; k0 < K; k0 += 64) {
    __syncthreads();
#pragma unroll
    for (int i = 0; i < 4; ++i) {
      int row = w * 32 + i * 8 + (lane >> 3);
      int sc_ = bcol ^ ((row & 7) << 4);
      if constexpr (AF32) {
        // A fp32: load 32B, cvt to 16B bf16, write swizzled directly
        const char* src = AB + (size_t)(m0 + row) * (K * 4) + k0 * 4 + (lane & 7) * 32;
        float4 f0 = *reinterpret_cast<const float4*>(src);
        float4 f1 = *reinterpret_cast<const float4*>(src + 16);
        int4 pk;
        pk.x = cvtpk_bf16(f0.x, f0.y);
        pk.y = cvtpk_bf16(f0.z, f0.w);
        pk.z = cvtpk_bf16(f1.x, f1.y);
        pk.w = cvtpk_bf16(f1.z, f1.w);
        *reinterpret_cast<int4*>(Ab8 + swz(row, bcol)) = pk;
      } else {
        gload16(AB + (size_t)(m0 + row) * (K * 2) + k0 * 2 + sc_, Ab8 + w * 4096 + i * 1024);
      }
      gload16(BB + (size_t)(n0 + row) * (K * 2) + k0 * 2 + sc_, Bb8 + w * 4096 + i * 1024);
    }
    __syncthreads();  // drains vmcnt+lgkm -> tile staged
#pragma unroll
    for (int ks = 0; ks < 2; ++ks) {
      bf16x8 af[4], bfr[4];
#pragma unroll
      for (int m = 0; m < 4; ++m) {
        int ar = wr * 64 + m * 16 + fr;
        af[m] = *reinterpret_cast<const bf16x8*>(Ab8 + swz(ar, ks * 64 + fq * 16));
      }
#pragma unroll
      for (int n = 0; n < 4; ++n) {
        int br = wc * 64 + n * 16 + fr;
        bfr[n] = *reinterpret_cast<const bf16x8*>(Bb8 + swz(br, ks * 64 + fq * 16));
      }
#pragma unroll
      for (int m = 0; m < 4; ++m)
#pragma unroll
        for (int n = 0; n < 4; ++n)
          acc[m][n] = __builtin_amdgcn_mfma_f32_16x16x32_bf16(af[m], bfr[n], acc[m][n], 0, 0, 0);
    }
  }

#pragma unroll
  for (int n = 0; n < 4; ++n) {
    int col = n0 + wc * 64 + n * 16 + fr;
    float bv = bias[col];
#pragma unroll
    for (int m = 0; m < 4; ++m) {
      int rowb = m0 + wr * 64 + m * 16 + fq * 4;
      if (mode == 2) {
        int b = rowb >> 11, s0 = rowb & (SEQ - 1);
        int h = col >> 6, d = col & 63;
        int2 pk;
        pk.x = cvtpk_bf16((acc[m][n][0] + bv) * oscale, (acc[m][n][1] + bv) * oscale);
        pk.y = cvtpk_bf16((acc[m][n][2] + bv) * oscale, (acc[m][n][3] + bv) * oscale);
        *reinterpret_cast<int2*>(
            &reinterpret_cast<unsigned short*>(C)[((size_t)((b * NHEAD + h) * HDIM + d)) * SEQ + s0]) = pk;
      } else if (mode == 0) {
#pragma unroll
        for (int r = 0; r < 4; ++r) {
          int row = rowb + r;
          float v = (acc[m][n][r] + bv) * oscale;
          int b = row >> 11, s = row & (SEQ - 1), h = col >> 6, d = col & 63;
          reinterpret_cast<unsigned short*>(C)[((size_t)((b * NHEAD + h) * SEQ + s) << 6) + d] = f2bf(v);
        }
      } else {
#pragma unroll
        for (int r = 0; r < 4; ++r)
          reinterpret_cast<float*>(C)[(size_t)(rowb + r) * EMBED + col] = acc[m][n][r] + bv;
      }
    }
  }
}

// fused QKV projection with in-staging cvt: blockIdx.z picks {Q, K, V}.
__global__ __launch_bounds__(256) void gemm_qkv(
    const float* __restrict__ Xq, const float* __restrict__ Xk, const float* __restrict__ Xv,
    const unsigned short* __restrict__ Wqt, const unsigned short* __restrict__ Wkt,
    const unsigned short* __restrict__ Wvt,
    const float* __restrict__ bq, const float* __restrict__ bk, const float* __restrict__ bv,
    unsigned short* __restrict__ Qb, unsigned short* __restrict__ Kb,
    unsigned short* __restrict__ Vtb, float qscale) {
  switch (blockIdx.z) {
    case 0: gemm_core<true>(Xq, Wqt, bq, Qb, qscale, 0); break;
    case 1: gemm_core<true>(Xk, Wkt, bk, Kb, 1.0f, 0); break;
    default: gemm_core<true>(Xv, Wvt, bv, Vtb, 1.0f, 2); break;
  }
}

__global__ __launch_bounds__(256) void gemm_out(const unsigned short* __restrict__ A,
                                                const unsigned short* __restrict__ Bt,
                                                const float* __restrict__ bias,
                                                float* __restrict__ C) {
  gemm_core<false>(A, Bt, bias, C, 1.0f, 1);
}

// ---- flash attention (round-6 verified version, unchanged) ----
// Q,K bf16 [B*H][S][D] (Q pre-scaled by log2e/8); Vt bf16 [B*H][D][S].
// Swapped QK^T: sc = mfma(K,Q) -> S^T, all 64 k-scores for q=fr in-lane.
// T14 reg-staged double buffer: global->regs issued before compute (latency
// hides under QK/softmax/PV), ds_write to the other buffer after compute,
// one __syncthreads per tile. No manual waitcnt (register deps order loads).
// Defer-max: skip O-rescale while tile max stays within 2^8 of running max.
__global__ __launch_bounds__(256) void attn(const unsigned short* __restrict__ Q,
                                            const unsigned short* __restrict__ Kk,
                                            const unsigned short* __restrict__ Vt,
                                            unsigned short* __restrict__ AO) {
  __shared__ __align__(16) unsigned short Klds[2][64 * 64];
  __shared__ __align__(16) unsigned short Vlds[2][64 * 64];  // [d][k]
  __shared__ __align__(16) unsigned short Plds[4][16 * 64];
  const int tid = threadIdx.x, lane = tid & 63, w = tid >> 6;
  const int fr = lane & 15, fq = lane >> 4;
  char* Pb8 = (char*)&Plds[w][0];

  // XCD swizzle: all 32 q-blocks of a head on one XCD (round-robin lin%8).
  const int lin = blockIdx.x;
  const int head = (lin & 7) * 4 + ((lin >> 3) & 3);
  const int q0 = (lin >> 5) * 64;
  const size_t hb = (size_t)head * SEQ * HDIM;
  const unsigned short* Qh = Q + hb;
  const char* KhB = (const char*)(Kk + hb);
  const char* VhB = (const char*)(Vt + hb);  // rows d, 4096B each

  // staging addressing (both-sides swizzle, rule #21):
  //   global col-byte: ((lane&7)*16) ^ ((lane>>3)<<4)   [loop-invariant]
  //   LDS write: linear, base + lane*16  -> reads use swz(row, bcol)
  const int gsc = ((lane & 7) * 16) ^ ((lane >> 3) << 4);
  const int row0 = w * 16 + (lane >> 3);       // i=0 row; i=1 adds 8
  const int lwr = w * 2048 + lane * 16;        // LDS write byte offset, i=0

  int4 kreg0, kreg1, vreg0, vreg1;
#define LOADREGS(kt_)                                                                  \
  {                                                                                    \
    kreg0 = *reinterpret_cast<const int4*>(KhB + (size_t)((kt_)*64 + row0) * 128 + gsc);       \
    kreg1 = *reinterpret_cast<const int4*>(KhB + (size_t)((kt_)*64 + row0 + 8) * 128 + gsc);   \
    vreg0 = *reinterpret_cast<const int4*>(VhB + (size_t)row0 * (SEQ * 2) + (kt_)*128 + gsc);  \
    vreg1 = *reinterpret_cast<const int4*>(VhB + (size_t)(row0 + 8) * (SEQ * 2) + (kt_)*128 + gsc); \
  }
#define WRITEREGS(b_)                                                 \
  {                                                                   \
    *reinterpret_cast<int4*>((char*)Klds[b_] + lwr) = kreg0;          \
    *reinterpret_cast<int4*>((char*)Klds[b_] + lwr + 1024) = kreg1;   \
    *reinterpret_cast<int4*>((char*)Vlds[b_] + lwr) = vreg0;          \
    *reinterpret_cast<int4*>((char*)Vlds[b_] + lwr + 1024) = vreg1;   \
  }

  bf16x8 qf[2];
  {
    size_t qoff = (size_t)(q0 + w * 16 + fr) * HDIM + fq * 8;
    qf[0] = *reinterpret_cast<const bf16x8*>(&Qh[qoff]);
    qf[1] = *reinterpret_cast<const bf16x8*>(&Qh[qoff + 32]);
  }
  f32x4 oacc[4];
#pragma unroll
  for (int n = 0; n < 4; ++n) oacc[n] = f32x4{0.f, 0.f, 0.f, 0.f};
  float mrow = -1e30f, lrow = 0.f;
  const int rsrc = (fq << 4) + (fq << 2);  // lane fq*16 + fq*4 (+rr): stats for q=fq*4+rr

  LOADREGS(0);
  WRITEREGS(0);
  __syncthreads();

  for (int kt = 0; kt < SEQ / 64; ++kt) {
    const int cur = kt & 1;
    char* Kb8 = (char*)Klds[cur];
    char* Vb8 = (char*)Vlds[cur];
    const bool more = (kt + 1 < SEQ / 64);
    if (more) LOADREGS(kt + 1);  // async: latency hides under this tile's compute

    // S^T = K·Q^T: sc[n] rows k = n*16+fq*4+r, col q = fr (log2 domain)
    f32x4 sc[4];
#pragma unroll
    for (int n = 0; n < 4; ++n) {
      int kr = n * 16 + fr;
      bf16x8 k0 = *reinterpret_cast<const bf16x8*>(Kb8 + swz(kr, fq * 16));
      bf16x8 k1 = *reinterpret_cast<const bf16x8*>(Kb8 + swz(kr, 64 + fq * 16));
      f32x4 a = f32x4{0.f, 0.f, 0.f, 0.f};
      a = __builtin_amdgcn_mfma_f32_16x16x32_bf16(k0, qf[0], a, 0, 0, 0);
      a = __builtin_amdgcn_mfma_f32_16x16x32_bf16(k1, qf[1], a, 0, 0, 0);
      sc[n] = a;
    }

    // tile max for this lane's q (=fr): 16 in-lane + 2 cross-lane
    float mx0 = fmaxf(fmaxf(sc[0][0], sc[0][1]), fmaxf(sc[0][2], sc[0][3]));
    float mx1 = fmaxf(fmaxf(sc[1][0], sc[1][1]), fmaxf(sc[1][2], sc[1][3]));
    float mx2 = fmaxf(fmaxf(sc[2][0], sc[2][1]), fmaxf(sc[2][2], sc[2][3]));
    float mx3 = fmaxf(fmaxf(sc[3][0], sc[3][1]), fmaxf(sc[3][2], sc[3][3]));
    float mt = fmaxf(fmaxf(mx0, mx1), fmaxf(mx2, mx3));
    mt = fmaxf(mt, __shfl_xor(mt, 16));
    mt = fmaxf(mt, __shfl_xor(mt, 32));

    // T13 defer-max: only rescale when some row's max grew past 2^8 headroom
    if (!__all(mt <= mrow + 8.0f)) {
      float mn = fmaxf(mrow, mt);
      float resc = exp2f(mrow - mn);
      lrow *= resc;
      float rq[4];
#pragma unroll
      for (int rr = 0; rr < 4; ++rr) rq[rr] = __shfl(resc, rsrc + rr, 64);
#pragma unroll
      for (int n = 0; n < 4; ++n)
#pragma unroll
        for (int rr = 0; rr < 4; ++rr) oacc[n][rr] *= rq[rr];
      mrow = mn;
    }

    float p[4][4];
    float ps = 0.f;
#pragma unroll
    for (int n = 0; n < 4; ++n)
#pragma unroll
      for (int r = 0; r < 4; ++r) {
        p[n][r] = exp2f(sc[n][r] - mrow);
        ps += p[n][r];
      }
    ps += __shfl_xor(ps, 16);
    ps += __shfl_xor(ps, 32);
    lrow += ps;

    // P -> Plds[q=fr][k] (swizzled), 4x ds_write_b64 via cvt_pk; k = n*16+fq*4+r
#pragma unroll
    for (int n = 0; n < 4; ++n) {
      int2 pk;
      pk.x = cvtpk_bf16(p[n][0], p[n][1]);
      pk.y = cvtpk_bf16(p[n][2], p[n][3]);
      *reinterpret_cast<int2*>(Pb8 + swz(fr, n * 32 + fq * 8)) = pk;
    }

    bf16x8 pa0 = *reinterpret_cast<const bf16x8*>(Pb8 + swz(fr, fq * 16));
    bf16x8 pa1 = *reinterpret_cast<const bf16x8*>(Pb8 + swz(fr, 64 + fq * 16));
#pragma unroll
    for (int n = 0; n < 4; ++n) {
      int dr = n * 16 + fr;
      bf16x8 vb0 = *reinterpret_cast<const bf16x8*>(Vb8 + swz(dr, fq * 16));
      bf16x8 vb1 = *reinterpret_cast<const bf16x8*>(Vb8 + swz(dr, 64 + fq * 16));
      oacc[n] = __builtin_amdgcn_mfma_f32_16x16x32_bf16(pa0, vb0, oacc[n], 0, 0, 0);
      oacc[n] = __builtin_amdgcn_mfma_f32_16x16x32_bf16(pa1, vb1, oacc[n], 0, 0, 0);
    }

    if (more) WRITEREGS(cur ^ 1);  // compiler waits loads via reg dep; buffer
                                   // free: all waves passed last barrier
    __syncthreads();
  }
#undef LOADREGS
#undef WRITEREGS

  const int b = head >> 4, h = head & 15;
  float lr[4];
#pragma unroll
  for (int rr = 0; rr < 4; ++rr) lr[rr] = __shfl(lrow, rsrc + rr, 64);
#pragma unroll
  for (int rr = 0; rr < 4; ++rr) {
    float inv = 1.0f / lr[rr];
    int srow = q0 + w * 16 + fq * 4 + rr;
    size_t ob = (size_t)(b * SEQ + srow) * EMBED + h * 64;
#pragma unroll
    for (int n = 0; n < 4; ++n) AO[ob + n * 16 + fr] = f2bf(oacc[n][rr] * inv);
  }
}

extern "C" void kernel_launch(void* const* d_in, const int* in_sizes, int n_in,
                              void* d_out, int out_size, void* d_ws, size_t ws_size,
                              hipStream_t stream) {
  const float* q32 = (const float*)d_in[0];
  const float* k32 = (const float*)d_in[1];
  const float* v32 = (const float*)d_in[2];
  const float* Wq = (const float*)d_in[3]; const float* bq = (const float*)d_in[4];
  const float* Wk = (const float*)d_in[5]; const float* bk = (const float*)d_in[6];
  const float* Wv = (const float*)d_in[7]; const float* bv = (const float*)d_in[8];
  const float* Wo = (const float*)d_in[9]; const float* bo = (const float*)d_in[10];
  float* out = (float*)d_out;

  char* ws = (char*)d_ws;
  const size_t MB = 1u << 20;
  unsigned short* AO  = (unsigned short*)(ws + 0 * MB);   // attn output bf16
  unsigned short* Wqt = (unsigned short*)(ws + 24 * MB);
  unsigned short* Wkt = (unsigned short*)(ws + 26 * MB);
  unsigned short* Wvt = (unsigned short*)(ws + 28 * MB);
  unsigned short* Wot = (unsigned short*)(ws + 30 * MB);
  unsigned short* Qb  = (unsigned short*)(ws + 32 * MB);
  unsigned short* Kb  = (unsigned short*)(ws + 40 * MB);
  unsigned short* Vtb = (unsigned short*)(ws + 48 * MB);

  wtrans<<<dim3(16, 16, 4), 256, 0, stream>>>(Wq, Wk, Wv, Wo, Wqt, Wkt, Wvt, Wot);

  const float qscale = 0.125f * 1.44269504088896340736f;  // (1/sqrt(64)) * log2(e)
  gemm_qkv<<<dim3(EMBED / 128, MROWS / 128, 3), 256, 0, stream>>>(
      q32, k32, v32, Wqt, Wkt, Wvt, bq, bk, bv, Qb, Kb, Vtb, qscale);

  attn<<<dim3(SEQ / 64 * 32), 256, 0, stream>>>(Qb, Kb, Vtb, AO);

  gemm_out<<<dim3(EMBED / 128, MROWS / 128), 256, 0, stream>>>(AO, Wot, bo, out);
}

// Round 9
// 152.842 us; speedup vs baseline: 2.0612x; 1.1430x over previous
//
#include <hip/hip_runtime.h>
#include <hip/hip_bf16.h>

// Problem: B=2, S=2048, E=1024, H=16, D=64. All inputs fp32, output fp32.
// Pipeline: cvt X->bf16 | wtrans W->bf16 [N][K] | fused QKV GEMM (grid.z=3,
//           BN=128) -> Q(scaled log2e/8),K [BH][S][D], V^T [BH][D][S]
//           | flash attention (2-wave blocks, 32q/wave, gload_lds prefetch
//           dbuf + 1 full-drain barrier/tile, swapped QK^T, exp2 softmax,
//           defer-max T13, cvt_pk T12) | GEMM BN=64 (2 blocks/CU) -> fp32+bo.
// LDS tiles: T2 XOR swizzle byte ^= ((row&7)<<4) within 128B rows; staged via
// global_load_lds with inverse-swizzled global source (linear LDS dest).
// History: r3 dbuf+counted-vmcnt raced -> full-drain barriers only.
//          r7 zero-staging attn latency-bound (MfmaUtil 5.8%) -> LDS staging
//          is mandatory in front of MFMA operands.
//          r8 AF32 cvt-fusion into GEMM-A regressed 23us -> separate cvt pass.

#define EMBED 1024
#define NHEAD 16
#define HDIM 64
#define SEQ 2048
#define MROWS 4096  // B*S

typedef __attribute__((ext_vector_type(8))) __bf16 bf16x8;
typedef __attribute__((ext_vector_type(4))) float f32x4;

__device__ __forceinline__ unsigned short f2bf(float f) {
  unsigned int u = __builtin_bit_cast(unsigned int, f);
  u += 0x7fffu + ((u >> 16) & 1u);  // round-to-nearest-even
  return (unsigned short)(u >> 16);
}

// packed f32x2 -> bf16x2 (T12 recipe; no builtin on gfx950)
__device__ __forceinline__ int cvtpk_bf16(float lo, float hi) {
  int r;
  asm("v_cvt_pk_bf16_f32 %0, %1, %2" : "=v"(r) : "v"(lo), "v"(hi));
  return r;
}

// swizzled byte offset within a [rows][128B] LDS tile
__device__ __forceinline__ int swz(int row, int bcol) {
  return row * 128 + (bcol ^ ((row & 7) << 4));
}

// async global->LDS, 16B per lane. LDS dest = base + lane*16 (linear).
__device__ __forceinline__ void gload16(const void* g, void* l) {
  __builtin_amdgcn_global_load_lds((const __attribute__((address_space(1))) void*)g,
                                   (__attribute__((address_space(3))) void*)l, 16, 0, 0);
}

// ---- fp32 -> bf16, 8 elements/thread; blockIdx.y selects src/dst ----
__global__ __launch_bounds__(256) void cvt_f32_bf16(const float* __restrict__ i0, const float* __restrict__ i1,
                                                    const float* __restrict__ i2,
                                                    unsigned short* __restrict__ o0, unsigned short* __restrict__ o1,
                                                    unsigned short* __restrict__ o2) {
  const float* in; unsigned short* out;
  switch (blockIdx.y) {
    case 0: in = i0; out = o0; break;
    case 1: in = i1; out = o1; break;
    default: in = i2; out = o2; break;
  }
  int i = blockIdx.x * 256 + threadIdx.x;
  const float4* p = reinterpret_cast<const float4*>(in) + (size_t)i * 2;
  float4 a = p[0], b = p[1];
  int4 r;
  r.x = cvtpk_bf16(a.x, a.y);
  r.y = cvtpk_bf16(a.z, a.w);
  r.z = cvtpk_bf16(b.x, b.y);
  r.w = cvtpk_bf16(b.z, b.w);
  reinterpret_cast<int4*>(out)[i] = r;
}

// ---- W [K][N] fp32 -> Wt [N][K] bf16, 64x64 LDS tiles ----
__global__ __launch_bounds__(256) void wtrans(const float* __restrict__ w0, const float* __restrict__ w1,
                                              const float* __restrict__ w2, const float* __restrict__ w3,
                                              unsigned short* __restrict__ o0, unsigned short* __restrict__ o1,
                                              unsigned short* __restrict__ o2, unsigned short* __restrict__ o3) {
  __shared__ float tile[64][65];
  const float* src; unsigned short* dst;
  switch (blockIdx.z) {
    case 0: src = w0; dst = o0; break;
    case 1: src = w1; dst = o1; break;
    case 2: src = w2; dst = o2; break;
    default: src = w3; dst = o3; break;
  }
  const int k0 = blockIdx.y * 64, n0 = blockIdx.x * 64;
  const int c = threadIdx.x & 63, r0 = threadIdx.x >> 6;
#pragma unroll
  for (int i = 0; i < 16; ++i) {
    int r = r0 + i * 4;
    tile[r][c] = src[(size_t)(k0 + r) * EMBED + n0 + c];
  }
  __syncthreads();
#pragma unroll
  for (int i = 0; i < 16; ++i) {
    int nr = r0 + i * 4;
    dst[(size_t)(n0 + nr) * EMBED + k0 + c] = f2bf(tile[c][nr]);
  }
}

// ---- shared GEMM core: C[128 x BN tile] = A @ Bt^T + bias, then *oscale ----
// A bf16 [M][K]; Bt bf16 [N][K]. Staging via global_load_lds (m97 pattern).
// BN=128: waves 2x2, acc[4][4].  BN=64: waves 4x1, acc[2][4] (2 blocks/CU).
// mode 0: bf16 scatter to [B*H][S][D]; mode 1: fp32 row-major;
// mode 2: bf16 V^T scatter to [B*H][D][S], 4 s-packed per 8B store.
template <int BN>
__device__ __forceinline__ void gemm_core(const unsigned short* __restrict__ A,
                                          const unsigned short* __restrict__ Bt,
                                          const float* __restrict__ bias,
                                          void* __restrict__ C, float oscale, int mode) {
  constexpr int K = EMBED;
  constexpr int MF = (BN == 128) ? 4 : 2;     // 16-row fragments per wave (M)
  constexpr int BRW = BN / 4;                 // B rows staged per wave
  __shared__ __align__(16) unsigned short Alds[128 * 64];
  __shared__ __align__(16) unsigned short Blds[BN * 64];
  char* Ab8 = (char*)Alds; char* Bb8 = (char*)Blds;
  const char* AB = (const char*)A;
  const char* BB = (const char*)Bt;
  const int tid = threadIdx.x;
  const int lane = tid & 63, w = tid >> 6;
  const int wr = (BN == 128) ? (w >> 1) : w;
  const int wc = (BN == 128) ? (w & 1) : 0;
  const int fr = lane & 15, fq = lane >> 4;
  const int m0 = blockIdx.y * 128, n0 = blockIdx.x * BN;
  const int bcol = (lane & 7) * 16;
  const int gsc = bcol ^ ((lane >> 3) << 4);  // row&7 == lane>>3 for all staged rows

  f32x4 acc[MF][4];
#pragma unroll
  for (int m = 0; m < MF; ++m)
#pragma unroll
    for (int n = 0; n < 4; ++n) acc[m][n] = f32x4{0.f, 0.f, 0.f, 0.f};

  for (int k0 = 0; k0 < K; k0 += 64) {
    __syncthreads();
#pragma unroll
    for (int i = 0; i < 4; ++i) {
      int row = w * 32 + i * 8 + (lane >> 3);
      gload16(AB + (size_t)(m0 + row) * (K * 2) + k0 * 2 + gsc, Ab8 + w * 4096 + i * 1024);
    }
#pragma unroll
    for (int i = 0; i < BRW / 8; ++i) {
      int row = w * BRW + i * 8 + (lane >> 3);
      gload16(BB + (size_t)(n0 + row) * (K * 2) + k0 * 2 + gsc, Bb8 + w * (BRW * 128) + i * 1024);
    }
    __syncthreads();  // drains vmcnt(0) -> tile staged
#pragma unroll
    for (int ks = 0; ks < 2; ++ks) {
      bf16x8 af[MF], bfr[4];
#pragma unroll
      for (int m = 0; m < MF; ++m) {
        int ar = wr * (MF * 16) + m * 16 + fr;
        af[m] = *reinterpret_cast<const bf16x8*>(Ab8 + swz(ar, ks * 64 + fq * 16));
      }
#pragma unroll
      for (int n = 0; n < 4; ++n) {
        int br = wc * 64 + n * 16 + fr;
        bfr[n] = *reinterpret_cast<const bf16x8*>(Bb8 + swz(br, ks * 64 + fq * 16));
      }
#pragma unroll
      for (int m = 0; m < MF; ++m)
#pragma unroll
        for (int n = 0; n < 4; ++n)
          acc[m][n] = __builtin_amdgcn_mfma_f32_16x16x32_bf16(af[m], bfr[n], acc[m][n], 0, 0, 0);
    }
  }

#pragma unroll
  for (int n = 0; n < 4; ++n) {
    int col = n0 + wc * 64 + n * 16 + fr;
    float bv = bias[col];
#pragma unroll
    for (int m = 0; m < MF; ++m) {
      int rowb = m0 + wr * (MF * 16) + m * 16 + fq * 4;
      if (mode == 2) {
        int b = rowb >> 11, s0 = rowb & (SEQ - 1);
        int h = col >> 6, d = col & 63;
        int2 pk;
        pk.x = cvtpk_bf16((acc[m][n][0] + bv) * oscale, (acc[m][n][1] + bv) * oscale);
        pk.y = cvtpk_bf16((acc[m][n][2] + bv) * oscale, (acc[m][n][3] + bv) * oscale);
        *reinterpret_cast<int2*>(
            &reinterpret_cast<unsigned short*>(C)[((size_t)((b * NHEAD + h) * HDIM + d)) * SEQ + s0]) = pk;
      } else if (mode == 0) {
#pragma unroll
        for (int r = 0; r < 4; ++r) {
          int row = rowb + r;
          float v = (acc[m][n][r] + bv) * oscale;
          int b = row >> 11, s = row & (SEQ - 1), h = col >> 6, d = col & 63;
          reinterpret_cast<unsigned short*>(C)[((size_t)((b * NHEAD + h) * SEQ + s) << 6) + d] = f2bf(v);
        }
      } else {
#pragma unroll
        for (int r = 0; r < 4; ++r)
          reinterpret_cast<float*>(C)[(size_t)(rowb + r) * EMBED + col] = acc[m][n][r] + bv;
      }
    }
  }
}

// fused QKV projection: blockIdx.z picks {Q, K, V}; 768 blocks = 3/CU.
__global__ __launch_bounds__(256) void gemm_qkv(
    const unsigned short* __restrict__ Xq, const unsigned short* __restrict__ Xk,
    const unsigned short* __restrict__ Xv,
    const unsigned short* __restrict__ Wqt, const unsigned short* __restrict__ Wkt,
    const unsigned short* __restrict__ Wvt,
    const float* __restrict__ bq, const float* __restrict__ bk, const float* __restrict__ bv,
    unsigned short* __restrict__ Qb, unsigned short* __restrict__ Kb,
    unsigned short* __restrict__ Vtb, float qscale) {
  switch (blockIdx.z) {
    case 0: gemm_core<128>(Xq, Wqt, bq, Qb, qscale, 0); break;
    case 1: gemm_core<128>(Xk, Wkt, bk, Kb, 1.0f, 0); break;
    default: gemm_core<128>(Xv, Wvt, bv, Vtb, 1.0f, 2); break;
  }
}

// output GEMM: 128x64 tiles -> 512 blocks = 2/CU (hide barrier drains)
__global__ __launch_bounds__(256) void gemm_out(const unsigned short* __restrict__ A,
                                                const unsigned short* __restrict__ Bt,
                                                const float* __restrict__ bias,
                                                float* __restrict__ C) {
  gemm_core<64>(A, Bt, bias, C, 1.0f, 1);
}

// ---- flash attention ----
// Q,K bf16 [B*H][S][D] (Q pre-scaled by log2e/8); Vt bf16 [B*H][D][S].
// 2 waves x 32 q-rows per block (64q), KBLK=64. Swapped QK^T per 16q half:
// sc = mfma(K,Q) -> S^T, 64 k-scores for q=fr in-lane. Staging: gload_lds
// prefetch into buf^1 at tile top; ONE full-drain __syncthreads at tile end
// (prefetch latency hides under ~2000cy of compute; no manual vmcnt).
// Defer-max T13: skip O-rescale while tile max within 2^8 of running max.
__global__ __launch_bounds__(128) void attn(const unsigned short* __restrict__ Q,
                                            const unsigned short* __restrict__ Kk,
                                            const unsigned short* __restrict__ Vt,
                                            unsigned short* __restrict__ AO) {
  __shared__ __align__(16) unsigned short Klds[2][64 * 64];
  __shared__ __align__(16) unsigned short Vlds[2][64 * 64];  // [d][k]
  __shared__ __align__(16) unsigned short Plds[2][16 * 64];
  const int tid = threadIdx.x, lane = tid & 63, w = tid >> 6;  // w in {0,1}
  const int fr = lane & 15, fq = lane >> 4;
  char* Pb8 = (char*)&Plds[w][0];

  // XCD swizzle: all 32 q-blocks of a head on one XCD (round-robin lin%8).
  const int lin = blockIdx.x;
  const int head = (lin & 7) * 4 + ((lin >> 3) & 3);
  const int q0 = (lin >> 5) * 64;
  const size_t hb = (size_t)head * SEQ * HDIM;
  const unsigned short* Qh = Q + hb;
  const char* KhB = (const char*)(Kk + hb);
  const char* VhB = (const char*)(Vt + hb);  // rows d, 4096B each

  // staging addressing (both-sides swizzle, rule #21): global source col
  // pre-XOR'd, LDS dest linear (base + lane*16), reads use swz(row, bcol).
  const int gsc = ((lane & 7) * 16) ^ ((lane >> 3) << 4);
  const int row0 = w * 32 + (lane >> 3);  // +i*8, i=0..3 -> 32 rows/wave

#define STAGE(kt_, b_)                                                                     \
  {                                                                                        \
    char* kb_ = (char*)Klds[b_];                                                           \
    char* vb_ = (char*)Vlds[b_];                                                           \
    _Pragma("unroll") for (int i_ = 0; i_ < 4; ++i_) {                                     \
      gload16(KhB + (size_t)((kt_)*64 + row0 + i_ * 8) * 128 + gsc,                        \
              kb_ + w * 4096 + i_ * 1024);                                                 \
      gload16(VhB + (size_t)(row0 + i_ * 8) * (SEQ * 2) + (kt_)*128 + gsc,                 \
              vb_ + w * 4096 + i_ * 1024);                                                 \
    }                                                                                      \
  }

  bf16x8 qf[2][2];
#pragma unroll
  for (int h = 0; h < 2; ++h) {
    size_t qoff = (size_t)(q0 + w * 32 + h * 16 + fr) * HDIM + fq * 8;
    qf[h][0] = *reinterpret_cast<const bf16x8*>(&Qh[qoff]);
    qf[h][1] = *reinterpret_cast<const bf16x8*>(&Qh[qoff + 32]);
  }
  f32x4 oacc[2][4];
#pragma unroll
  for (int h = 0; h < 2; ++h)
#pragma unroll
    for (int n = 0; n < 4; ++n) oacc[h][n] = f32x4{0.f, 0.f, 0.f, 0.f};
  float mrow[2] = {-1e30f, -1e30f}, lrow[2] = {0.f, 0.f};
  const int rsrc = (fq << 4) + (fq << 2);  // lane fq*16 + fq*4 (+rr): stats for q=fq*4+rr

  STAGE(0, 0);
  __syncthreads();  // drains vmcnt(0) -> tile 0 staged

  for (int kt = 0; kt < SEQ / 64; ++kt) {
    const int cur = kt & 1;
    const bool more = (kt + 1 < SEQ / 64);
    if (more) STAGE(kt + 1, cur ^ 1);  // async prefetch; drained by tile-end barrier
    char* Kb8 = (char*)Klds[cur];
    char* Vb8 = (char*)Vlds[cur];

#pragma unroll
    for (int h = 0; h < 2; ++h) {
      // S^T = K·Q^T: sc[n] rows k = n*16+fq*4+r, col q = fr (log2 domain)
      f32x4 sc[4];
#pragma unroll
      for (int n = 0; n < 4; ++n) {
        int kr = n * 16 + fr;
        bf16x8 k0 = *reinterpret_cast<const bf16x8*>(Kb8 + swz(kr, fq * 16));
        bf16x8 k1 = *reinterpret_cast<const bf16x8*>(Kb8 + swz(kr, 64 + fq * 16));
        f32x4 a = f32x4{0.f, 0.f, 0.f, 0.f};
        a = __builtin_amdgcn_mfma_f32_16x16x32_bf16(k0, qf[h][0], a, 0, 0, 0);
        a = __builtin_amdgcn_mfma_f32_16x16x32_bf16(k1, qf[h][1], a, 0, 0, 0);
        sc[n] = a;
      }

      // tile max for this lane's q (=fr): 16 in-lane + 2 cross-lane
      float mx0 = fmaxf(fmaxf(sc[0][0], sc[0][1]), fmaxf(sc[0][2], sc[0][3]));
      float mx1 = fmaxf(fmaxf(sc[1][0], sc[1][1]), fmaxf(sc[1][2], sc[1][3]));
      float mx2 = fmaxf(fmaxf(sc[2][0], sc[2][1]), fmaxf(sc[2][2], sc[2][3]));
      float mx3 = fmaxf(fmaxf(sc[3][0], sc[3][1]), fmaxf(sc[3][2], sc[3][3]));
      float mt = fmaxf(fmaxf(mx0, mx1), fmaxf(mx2, mx3));
      mt = fmaxf(mt, __shfl_xor(mt, 16));
      mt = fmaxf(mt, __shfl_xor(mt, 32));

      // T13 defer-max: only rescale when some row's max grew past 2^8 headroom
      if (!__all(mt <= mrow[h] + 8.0f)) {
        float mn = fmaxf(mrow[h], mt);
        float resc = __builtin_amdgcn_exp2f(mrow[h] - mn);
        lrow[h] *= resc;
        float rq[4];
#pragma unroll
        for (int rr = 0; rr < 4; ++rr) rq[rr] = __shfl(resc, rsrc + rr, 64);
#pragma unroll
        for (int n = 0; n < 4; ++n)
#pragma unroll
          for (int rr = 0; rr < 4; ++rr) oacc[h][n][rr] *= rq[rr];
        mrow[h] = mn;
      }

      float p[4][4];
      float ps = 0.f;
#pragma unroll
      for (int n = 0; n < 4; ++n)
#pragma unroll
        for (int r = 0; r < 4; ++r) {
          p[n][r] = __builtin_amdgcn_exp2f(sc[n][r] - mrow[h]);
          ps += p[n][r];
        }
      ps += __shfl_xor(ps, 16);
      ps += __shfl_xor(ps, 32);
      lrow[h] += ps;

      // P -> Plds[q=fr][k] (swizzled), 4x ds_write_b64 via cvt_pk
#pragma unroll
      for (int n = 0; n < 4; ++n) {
        int2 pk;
        pk.x = cvtpk_bf16(p[n][0], p[n][1]);
        pk.y = cvtpk_bf16(p[n][2], p[n][3]);
        *reinterpret_cast<int2*>(Pb8 + swz(fr, n * 32 + fq * 8)) = pk;
      }

      bf16x8 pa0 = *reinterpret_cast<const bf16x8*>(Pb8 + swz(fr, fq * 16));
      bf16x8 pa1 = *reinterpret_cast<const bf16x8*>(Pb8 + swz(fr, 64 + fq * 16));
#pragma unroll
      for (int n = 0; n < 4; ++n) {
        int dr = n * 16 + fr;
        bf16x8 vb0 = *reinterpret_cast<const bf16x8*>(Vb8 + swz(dr, fq * 16));
        bf16x8 vb1 = *reinterpret_cast<const bf16x8*>(Vb8 + swz(dr, 64 + fq * 16));
        oacc[h][n] = __builtin_amdgcn_mfma_f32_16x16x32_bf16(pa0, vb0, oacc[h][n], 0, 0, 0);
        oacc[h][n] = __builtin_amdgcn_mfma_f32_16x16x32_bf16(pa1, vb1, oacc[h][n], 0, 0, 0);
      }
    }

    __syncthreads();  // all waves done reading cur + prefetch drained (vmcnt 0)
  }
#undef STAGE

  const int b = head >> 4, hh = head & 15;
#pragma unroll
  for (int h = 0; h < 2; ++h) {
    float lr[4];
#pragma unroll
    for (int rr = 0; rr < 4; ++rr) lr[rr] = __shfl(lrow[h], rsrc + rr, 64);
#pragma unroll
    for (int rr = 0; rr < 4; ++rr) {
      float inv = 1.0f / lr[rr];
      int srow = q0 + w * 32 + h * 16 + fq * 4 + rr;
      size_t ob = (size_t)(b * SEQ + srow) * EMBED + hh * 64;
#pragma unroll
      for (int n = 0; n < 4; ++n) AO[ob + n * 16 + fr] = f2bf(oacc[h][n][rr] * inv);
    }
  }
}

extern "C" void kernel_launch(void* const* d_in, const int* in_sizes, int n_in,
                              void* d_out, int out_size, void* d_ws, size_t ws_size,
                              hipStream_t stream) {
  const float* q32 = (const float*)d_in[0];
  const float* k32 = (const float*)d_in[1];
  const float* v32 = (const float*)d_in[2];
  const float* Wq = (const float*)d_in[3]; const float* bq = (const float*)d_in[4];
  const float* Wk = (const float*)d_in[5]; const float* bk = (const float*)d_in[6];
  const float* Wv = (const float*)d_in[7]; const float* bv = (const float*)d_in[8];
  const float* Wo = (const float*)d_in[9]; const float* bo = (const float*)d_in[10];
  float* out = (float*)d_out;

  char* ws = (char*)d_ws;
  const size_t MB = 1u << 20;
  unsigned short* Xq  = (unsigned short*)(ws + 0 * MB);
  unsigned short* Xk  = (unsigned short*)(ws + 8 * MB);
  unsigned short* Xv  = (unsigned short*)(ws + 16 * MB);
  unsigned short* Wqt = (unsigned short*)(ws + 24 * MB);
  unsigned short* Wkt = (unsigned short*)(ws + 26 * MB);
  unsigned short* Wvt = (unsigned short*)(ws + 28 * MB);
  unsigned short* Wot = (unsigned short*)(ws + 30 * MB);
  unsigned short* Qb  = (unsigned short*)(ws + 32 * MB);
  unsigned short* Kb  = (unsigned short*)(ws + 40 * MB);
  unsigned short* Vtb = (unsigned short*)(ws + 48 * MB);
  unsigned short* AO  = Xq;  // safe: GEMM-Q (sole Xq reader) completes before attn writes

  const int n8 = (MROWS * EMBED) / 8;  // 524288
  cvt_f32_bf16<<<dim3(n8 / 256, 3), 256, 0, stream>>>(q32, k32, v32, Xq, Xk, Xv);
  wtrans<<<dim3(16, 16, 4), 256, 0, stream>>>(Wq, Wk, Wv, Wo, Wqt, Wkt, Wvt, Wot);

  const float qscale = 0.125f * 1.44269504088896340736f;  // (1/sqrt(64)) * log2(e)
  gemm_qkv<<<dim3(EMBED / 128, MROWS / 128, 3), 256, 0, stream>>>(
      Xq, Xk, Xv, Wqt, Wkt, Wvt, bq, bk, bv, Qb, Kb, Vtb, qscale);

  attn<<<dim3(SEQ / 64 * 32), 128, 0, stream>>>(Qb, Kb, Vtb, AO);

  gemm_out<<<dim3(EMBED / 64, MROWS / 128), 256, 0, stream>>>(AO, Wot, bo, out);
}

// Round 10
// 141.776 us; speedup vs baseline: 2.2221x; 1.0781x over previous
//
#include <hip/hip_runtime.h>
#include <hip/hip_bf16.h>

// Problem: B=2, S=2048, E=1024, H=16, D=64. All inputs fp32, output fp32.
// Pipeline: cvt X->bf16 | wtrans W->bf16 [N][K] | fused QKV GEMM (grid.z=3,
//           BN=128) -> Q(scaled log2e/8),K [BH][S][D], V^T [BH][D][S_perm]
//           (seq-quartets bit-swapped within each 16 so attn's PV A-fragment
//           slot->k mapping is in-lane) | flash attention (32x32x16 MFMA,
//           2-wave blocks, 32q/wave-lane q=lane&31, gload_lds prefetch dbuf +
//           1 full-drain barrier/tile, in-lane softmax + 1 shfl_xor(32),
//           defer-max T13, P in-register via cvt_pk only) | GEMM BN=64.
// LDS tiles: T2 XOR swizzle byte ^= ((row&7)<<4) within 128B rows; staged via
// global_load_lds with inverse-swizzled global source (linear LDS dest).
// History: r3 dbuf+counted-vmcnt raced -> full-drain barriers only.
//          r7 zero-staging attn latency-bound -> LDS staging mandatory.
//          r8 AF32 cvt-fusion regressed -> separate cvt pass.
//          r9 16q->32q/wave: VALU 71->45% but latency-bound at 8 waves/CU ->
//          r10 shortens the serial chain (16 MFMA, 16 LDS ops, 2 shfl/tile).

#define EMBED 1024
#define NHEAD 16
#define HDIM 64
#define SEQ 2048
#define MROWS 4096  // B*S

typedef __attribute__((ext_vector_type(8))) __bf16 bf16x8;
typedef __attribute__((ext_vector_type(4))) float f32x4;
typedef __attribute__((ext_vector_type(16))) float f32x16;

__device__ __forceinline__ unsigned short f2bf(float f) {
  unsigned int u = __builtin_bit_cast(unsigned int, f);
  u += 0x7fffu + ((u >> 16) & 1u);  // round-to-nearest-even
  return (unsigned short)(u >> 16);
}

// packed f32x2 -> bf16x2 (T12 recipe; no builtin on gfx950)
__device__ __forceinline__ int cvtpk_bf16(float lo, float hi) {
  int r;
  asm("v_cvt_pk_bf16_f32 %0, %1, %2" : "=v"(r) : "v"(lo), "v"(hi));
  return r;
}

// swizzled byte offset within a [rows][128B] LDS tile
__device__ __forceinline__ int swz(int row, int bcol) {
  return row * 128 + (bcol ^ ((row & 7) << 4));
}

// async global->LDS, 16B per lane. LDS dest = base + lane*16 (linear).
__device__ __forceinline__ void gload16(const void* g, void* l) {
  __builtin_amdgcn_global_load_lds((const __attribute__((address_space(1))) void*)g,
                                   (__attribute__((address_space(3))) void*)l, 16, 0, 0);
}

// ---- fp32 -> bf16, 8 elements/thread; blockIdx.y selects src/dst ----
__global__ __launch_bounds__(256) void cvt_f32_bf16(const float* __restrict__ i0, const float* __restrict__ i1,
                                                    const float* __restrict__ i2,
                                                    unsigned short* __restrict__ o0, unsigned short* __restrict__ o1,
                                                    unsigned short* __restrict__ o2) {
  const float* in; unsigned short* out;
  switch (blockIdx.y) {
    case 0: in = i0; out = o0; break;
    case 1: in = i1; out = o1; break;
    default: in = i2; out = o2; break;
  }
  int i = blockIdx.x * 256 + threadIdx.x;
  const float4* p = reinterpret_cast<const float4*>(in) + (size_t)i * 2;
  float4 a = p[0], b = p[1];
  int4 r;
  r.x = cvtpk_bf16(a.x, a.y);
  r.y = cvtpk_bf16(a.z, a.w);
  r.z = cvtpk_bf16(b.x, b.y);
  r.w = cvtpk_bf16(b.z, b.w);
  reinterpret_cast<int4*>(out)[i] = r;
}

// ---- W [K][N] fp32 -> Wt [N][K] bf16, 64x64 LDS tiles ----
__global__ __launch_bounds__(256) void wtrans(const float* __restrict__ w0, const float* __restrict__ w1,
                                              const float* __restrict__ w2, const float* __restrict__ w3,
                                              unsigned short* __restrict__ o0, unsigned short* __restrict__ o1,
                                              unsigned short* __restrict__ o2, unsigned short* __restrict__ o3) {
  __shared__ float tile[64][65];
  const float* src; unsigned short* dst;
  switch (blockIdx.z) {
    case 0: src = w0; dst = o0; break;
    case 1: src = w1; dst = o1; break;
    case 2: src = w2; dst = o2; break;
    default: src = w3; dst = o3; break;
  }
  const int k0 = blockIdx.y * 64, n0 = blockIdx.x * 64;
  const int c = threadIdx.x & 63, r0 = threadIdx.x >> 6;
#pragma unroll
  for (int i = 0; i < 16; ++i) {
    int r = r0 + i * 4;
    tile[r][c] = src[(size_t)(k0 + r) * EMBED + n0 + c];
  }
  __syncthreads();
#pragma unroll
  for (int i = 0; i < 16; ++i) {
    int nr = r0 + i * 4;
    dst[(size_t)(n0 + nr) * EMBED + k0 + c] = f2bf(tile[c][nr]);
  }
}

// ---- shared GEMM core: C[128 x BN tile] = A @ Bt^T + bias, then *oscale ----
// A bf16 [M][K]; Bt bf16 [N][K]. Staging via global_load_lds (m97 pattern).
// BN=128: waves 2x2, acc[4][4].  BN=64: waves 4x1, acc[2][4] (2 blocks/CU).
// mode 0: bf16 scatter to [B*H][S][D]; mode 1: fp32 row-major;
// mode 2: bf16 V^T scatter to [B*H][D][S] with seq-quartet bit-swap
//         (s-quartet q -> position-quartet ((q&1)<<1)|(q>>1)) so attn's PV
//         in-lane A-fragment permutation is compensated in V's layout.
template <int BN>
__device__ __forceinline__ void gemm_core(const unsigned short* __restrict__ A,
                                          const unsigned short* __restrict__ Bt,
                                          const float* __restrict__ bias,
                                          void* __restrict__ C, float oscale, int mode) {
  constexpr int K = EMBED;
  constexpr int MF = (BN == 128) ? 4 : 2;     // 16-row fragments per wave (M)
  constexpr int BRW = BN / 4;                 // B rows staged per wave
  __shared__ __align__(16) unsigned short Alds[128 * 64];
  __shared__ __align__(16) unsigned short Blds[BN * 64];
  char* Ab8 = (char*)Alds; char* Bb8 = (char*)Blds;
  const char* AB = (const char*)A;
  const char* BB = (const char*)Bt;
  const int tid = threadIdx.x;
  const int lane = tid & 63, w = tid >> 6;
  const int wr = (BN == 128) ? (w >> 1) : w;
  const int wc = (BN == 128) ? (w & 1) : 0;
  const int fr = lane & 15, fq = lane >> 4;
  const int m0 = blockIdx.y * 128, n0 = blockIdx.x * BN;
  const int bcol = (lane & 7) * 16;
  const int gsc = bcol ^ ((lane >> 3) << 4);  // row&7 == lane>>3 for all staged rows

  f32x4 acc[MF][4];
#pragma unroll
  for (int m = 0; m < MF; ++m)
#pragma unroll
    for (int n = 0; n < 4; ++n) acc[m][n] = f32x4{0.f, 0.f, 0.f, 0.f};

  for (int k0 = 0; k0 < K; k0 += 64) {
    __syncthreads();
#pragma unroll
    for (int i = 0; i < 4; ++i) {
      int row = w * 32 + i * 8 + (lane >> 3);
      gload16(AB + (size_t)(m0 + row) * (K * 2) + k0 * 2 + gsc, Ab8 + w * 4096 + i * 1024);
    }
#pragma unroll
    for (int i = 0; i < BRW / 8; ++i) {
      int row = w * BRW + i * 8 + (lane >> 3);
      gload16(BB + (size_t)(n0 + row) * (K * 2) + k0 * 2 + gsc, Bb8 + w * (BRW * 128) + i * 1024);
    }
    __syncthreads();  // drains vmcnt(0) -> tile staged
#pragma unroll
    for (int ks = 0; ks < 2; ++ks) {
      bf16x8 af[MF], bfr[4];
#pragma unroll
      for (int m = 0; m < MF; ++m) {
        int ar = wr * (MF * 16) + m * 16 + fr;
        af[m] = *reinterpret_cast<const bf16x8*>(Ab8 + swz(ar, ks * 64 + fq * 16));
      }
#pragma unroll
      for (int n = 0; n < 4; ++n) {
        int br = wc * 64 + n * 16 + fr;
        bfr[n] = *reinterpret_cast<const bf16x8*>(Bb8 + swz(br, ks * 64 + fq * 16));
      }
#pragma unroll
      for (int m = 0; m < MF; ++m)
#pragma unroll
        for (int n = 0; n < 4; ++n)
          acc[m][n] = __builtin_amdgcn_mfma_f32_16x16x32_bf16(af[m], bfr[n], acc[m][n], 0, 0, 0);
    }
  }

#pragma unroll
  for (int n = 0; n < 4; ++n) {
    int col = n0 + wc * 64 + n * 16 + fr;
    float bv = bias[col];
#pragma unroll
    for (int m = 0; m < MF; ++m) {
      int rowb = m0 + wr * (MF * 16) + m * 16 + fq * 4;
      if (mode == 2) {
        int b = rowb >> 11, s0 = rowb & (SEQ - 1);
        // seq-quartet bit-swap: quartet q -> ((q&1)<<1)|(q>>1) within each 16
        int s0p = (s0 & ~12) | ((s0 & 4) << 1) | ((s0 & 8) >> 1);
        int h = col >> 6, d = col & 63;
        int2 pk;
        pk.x = cvtpk_bf16((acc[m][n][0] + bv) * oscale, (acc[m][n][1] + bv) * oscale);
        pk.y = cvtpk_bf16((acc[m][n][2] + bv) * oscale, (acc[m][n][3] + bv) * oscale);
        *reinterpret_cast<int2*>(
            &reinterpret_cast<unsigned short*>(C)[((size_t)((b * NHEAD + h) * HDIM + d)) * SEQ + s0p]) = pk;
      } else if (mode == 0) {
#pragma unroll
        for (int r = 0; r < 4; ++r) {
          int row = rowb + r;
          float v = (acc[m][n][r] + bv) * oscale;
          int b = row >> 11, s = row & (SEQ - 1), h = col >> 6, d = col & 63;
          reinterpret_cast<unsigned short*>(C)[((size_t)((b * NHEAD + h) * SEQ + s) << 6) + d] = f2bf(v);
        }
      } else {
#pragma unroll
        for (int r = 0; r < 4; ++r)
          reinterpret_cast<float*>(C)[(size_t)(rowb + r) * EMBED + col] = acc[m][n][r] + bv;
      }
    }
  }
}

// fused QKV projection: blockIdx.z picks {Q, K, V}; 768 blocks = 3/CU.
__global__ __launch_bounds__(256) void gemm_qkv(
    const unsigned short* __restrict__ Xq, const unsigned short* __restrict__ Xk,
    const unsigned short* __restrict__ Xv,
    const unsigned short* __restrict__ Wqt, const unsigned short* __restrict__ Wkt,
    const unsigned short* __restrict__ Wvt,
    const float* __restrict__ bq, const float* __restrict__ bk, const float* __restrict__ bv,
    unsigned short* __restrict__ Qb, unsigned short* __restrict__ Kb,
    unsigned short* __restrict__ Vtb, float qscale) {
  switch (blockIdx.z) {
    case 0: gemm_core<128>(Xq, Wqt, bq, Qb, qscale, 0); break;
    case 1: gemm_core<128>(Xk, Wkt, bk, Kb, 1.0f, 0); break;
    default: gemm_core<128>(Xv, Wvt, bv, Vtb, 1.0f, 2); break;
  }
}

// output GEMM: 128x64 tiles -> 512 blocks = 2/CU (hide barrier drains)
__global__ __launch_bounds__(256) void gemm_out(const unsigned short* __restrict__ A,
                                                const unsigned short* __restrict__ Bt,
                                                const float* __restrict__ bias,
                                                float* __restrict__ C) {
  gemm_core<64>(A, Bt, bias, C, 1.0f, 1);
}

// ---- flash attention, 32x32x16 MFMA ----
// Q,K bf16 [B*H][S][D] (Q pre-scaled by log2e/8); Vt bf16 [B*H][D][S_perm].
// 2 waves x 32 q-rows per block. Lane: ql=lane&31 (q), t=lane>>5.
// QK: sc[kb] = mfma_32x32x16(Kfrag, Qfrag) -> C[k][q]: col q=ql (all 16 regs
//   this lane's q), row k=(reg&3)+8*(reg>>2)+4t within kb*32. [guide-verified]
// Softmax fully in-lane (32 scores) + one shfl_xor(32) merge.
// PV: A=P supplied from own regs (pa[s] = cvt_pk of regs 8*(s&1)..+7 of
//   sc[s>>1]); the resulting slot->k quartet permutation is compensated by
//   V^T's bit-swapped seq layout (producer mode 2) -> V reads contiguous.
// Staging: r9-verified gload_lds prefetch dbuf + 1 full-drain barrier/tile.
__global__ __launch_bounds__(128) void attn(const unsigned short* __restrict__ Q,
                                            const unsigned short* __restrict__ Kk,
                                            const unsigned short* __restrict__ Vt,
                                            unsigned short* __restrict__ AO) {
  __shared__ __align__(16) unsigned short Klds[2][64 * 64];
  __shared__ __align__(16) unsigned short Vlds[2][64 * 64];  // [d][k_perm]
  const int tid = threadIdx.x, lane = tid & 63, w = tid >> 6;  // w in {0,1}
  const int ql = lane & 31, t = lane >> 5;

  // XCD swizzle: all 32 q-blocks of a head on one XCD (round-robin lin%8).
  const int lin = blockIdx.x;
  const int head = (lin & 7) * 4 + ((lin >> 3) & 3);
  const int q0 = (lin >> 5) * 64;
  const size_t hb = (size_t)head * SEQ * HDIM;
  const unsigned short* Qh = Q + hb;
  const char* KhB = (const char*)(Kk + hb);
  const char* VhB = (const char*)(Vt + hb);  // rows d, 4096B each

  // staging addressing (both-sides swizzle, rule #21)
  const int gsc = ((lane & 7) * 16) ^ ((lane >> 3) << 4);
  const int row0 = w * 32 + (lane >> 3);  // +i*8, i=0..3 -> 32 rows/wave

#define STAGE(kt_, b_)                                                                     \
  {                                                                                        \
    char* kb_ = (char*)Klds[b_];                                                           \
    char* vb_ = (char*)Vlds[b_];                                                           \
    _Pragma("unroll") for (int i_ = 0; i_ < 4; ++i_) {                                     \
      gload16(KhB + (size_t)((kt_)*64 + row0 + i_ * 8) * 128 + gsc,                        \
              kb_ + w * 4096 + i_ * 1024);                                                 \
      gload16(VhB + (size_t)(row0 + i_ * 8) * (SEQ * 2) + (kt_)*128 + gsc,                 \
              vb_ + w * 4096 + i_ * 1024);                                                 \
    }                                                                                      \
  }

  // Q fragments (B-operand): lane supplies Q[ql][d = s*16 + t*8 + e]
  bf16x8 qf[4];
  {
    const unsigned short* qp = Qh + (size_t)(q0 + w * 32 + ql) * HDIM + t * 8;
    qf[0] = *reinterpret_cast<const bf16x8*>(qp);
    qf[1] = *reinterpret_cast<const bf16x8*>(qp + 16);
    qf[2] = *reinterpret_cast<const bf16x8*>(qp + 32);
    qf[3] = *reinterpret_cast<const bf16x8*>(qp + 48);
  }
  f32x16 oacc0 = {}, oacc1 = {};  // d-blocks 0..31, 32..63
  float mrow = -1e30f, lrow = 0.f;

  STAGE(0, 0);
  __syncthreads();  // drains vmcnt(0) -> tile 0 staged

  for (int kt = 0; kt < SEQ / 64; ++kt) {
    const int cur = kt & 1;
    const bool more = (kt + 1 < SEQ / 64);
    if (more) STAGE(kt + 1, cur ^ 1);  // async prefetch; drained by tile-end barrier
    char* Kb8 = (char*)Klds[cur];
    char* Vb8 = (char*)Vlds[cur];

    // S^T = K.Q^T (log2 domain): sc0 = keys kb=0 (k 0..31), sc1 = kb=1
    f32x16 sc0 = {}, sc1 = {};
#pragma unroll
    for (int s = 0; s < 4; ++s) {
      bf16x8 kf0 = *reinterpret_cast<const bf16x8*>(Kb8 + swz(ql, s * 32 + t * 16));
      bf16x8 kf1 = *reinterpret_cast<const bf16x8*>(Kb8 + swz(32 + ql, s * 32 + t * 16));
      sc0 = __builtin_amdgcn_mfma_f32_32x32x16_bf16(kf0, qf[s], sc0, 0, 0, 0);
      sc1 = __builtin_amdgcn_mfma_f32_32x32x16_bf16(kf1, qf[s], sc1, 0, 0, 0);
    }

    // in-lane max tree over 32 scores (all for q=ql), then merge halves
    float m8[8];
#pragma unroll
    for (int i = 0; i < 8; ++i)
      m8[i] = fmaxf(fmaxf(sc0[2 * i], sc0[2 * i + 1]), fmaxf(sc1[2 * i], sc1[2 * i + 1]));
    float m4a = fmaxf(m8[0], m8[1]), m4b = fmaxf(m8[2], m8[3]);
    float m4c = fmaxf(m8[4], m8[5]), m4d = fmaxf(m8[6], m8[7]);
    float mt = fmaxf(fmaxf(m4a, m4b), fmaxf(m4c, m4d));
    mt = fmaxf(mt, __shfl_xor(mt, 32));

    // T13 defer-max: only rescale when some row's max grew past 2^8 headroom
    if (!__all(mt <= mrow + 8.0f)) {
      float mn = fmaxf(mrow, mt);
      float resc = __builtin_amdgcn_exp2f(mrow - mn);
      lrow *= resc;
#pragma unroll
      for (int r = 0; r < 16; ++r) {
        float rq = __shfl(resc, (r & 3) + 8 * (r >> 2) + 4 * t, 64);
        oacc0[r] *= rq;
        oacc1[r] *= rq;
      }
      mrow = mn;
    }

    // P = exp2(S - mrow) in place; partial sums with 4-way ILP
    float ps0 = 0.f, ps1 = 0.f, ps2 = 0.f, ps3 = 0.f;
#pragma unroll
    for (int i = 0; i < 4; ++i) {
      sc0[4 * i + 0] = __builtin_amdgcn_exp2f(sc0[4 * i + 0] - mrow);
      sc0[4 * i + 1] = __builtin_amdgcn_exp2f(sc0[4 * i + 1] - mrow);
      sc0[4 * i + 2] = __builtin_amdgcn_exp2f(sc0[4 * i + 2] - mrow);
      sc0[4 * i + 3] = __builtin_amdgcn_exp2f(sc0[4 * i + 3] - mrow);
      sc1[4 * i + 0] = __builtin_amdgcn_exp2f(sc1[4 * i + 0] - mrow);
      sc1[4 * i + 1] = __builtin_amdgcn_exp2f(sc1[4 * i + 1] - mrow);
      sc1[4 * i + 2] = __builtin_amdgcn_exp2f(sc1[4 * i + 2] - mrow);
      sc1[4 * i + 3] = __builtin_amdgcn_exp2f(sc1[4 * i + 3] - mrow);
      ps0 += sc0[4 * i + 0] + sc0[4 * i + 1];
      ps1 += sc0[4 * i + 2] + sc0[4 * i + 3];
      ps2 += sc1[4 * i + 0] + sc1[4 * i + 1];
      ps3 += sc1[4 * i + 2] + sc1[4 * i + 3];
    }
    float ps = (ps0 + ps1) + (ps2 + ps3);
    ps += __shfl_xor(ps, 32);
    lrow += ps;

    // PA fragments: pa[s] = own regs 8*(s&1)..+7 of sc[s>>1] (no cross-lane;
    // slot->k quartet permutation is baked into V^T's global layout)
    int4 paw[4];
#pragma unroll
    for (int s2 = 0; s2 < 2; ++s2) {
      paw[s2].x     = cvtpk_bf16(sc0[8 * s2 + 0], sc0[8 * s2 + 1]);
      paw[s2].y     = cvtpk_bf16(sc0[8 * s2 + 2], sc0[8 * s2 + 3]);
      paw[s2].z     = cvtpk_bf16(sc0[8 * s2 + 4], sc0[8 * s2 + 5]);
      paw[s2].w     = cvtpk_bf16(sc0[8 * s2 + 6], sc0[8 * s2 + 7]);
      paw[2 + s2].x = cvtpk_bf16(sc1[8 * s2 + 0], sc1[8 * s2 + 1]);
      paw[2 + s2].y = cvtpk_bf16(sc1[8 * s2 + 2], sc1[8 * s2 + 3]);
      paw[2 + s2].z = cvtpk_bf16(sc1[8 * s2 + 4], sc1[8 * s2 + 5]);
      paw[2 + s2].w = cvtpk_bf16(sc1[8 * s2 + 6], sc1[8 * s2 + 7]);
    }

    // PV: O[q][d] += P.V; V-fragment (B-operand) rows d, positions s*16+slot
#pragma unroll
    for (int s = 0; s < 4; ++s) {
      bf16x8 pa = __builtin_bit_cast(bf16x8, paw[s]);
      bf16x8 v0 = *reinterpret_cast<const bf16x8*>(Vb8 + swz(ql, s * 32 + t * 16));
      bf16x8 v1 = *reinterpret_cast<const bf16x8*>(Vb8 + swz(32 + ql, s * 32 + t * 16));
      oacc0 = __builtin_amdgcn_mfma_f32_32x32x16_bf16(pa, v0, oacc0, 0, 0, 0);
      oacc1 = __builtin_amdgcn_mfma_f32_32x32x16_bf16(pa, v1, oacc1, 0, 0, 0);
    }

    __syncthreads();  // all waves done reading cur + prefetch drained (vmcnt 0)
  }
#undef STAGE

  const int b = head >> 4, hh = head & 15;
#pragma unroll
  for (int r = 0; r < 16; ++r) {
    int qr = (r & 3) + 8 * (r >> 2) + 4 * t;
    float inv = 1.0f / __shfl(lrow, qr, 64);
    int srow = q0 + w * 32 + qr;
    size_t ob = (size_t)(b * SEQ + srow) * EMBED + hh * 64 + ql;
    AO[ob] = f2bf(oacc0[r] * inv);
    AO[ob + 32] = f2bf(oacc1[r] * inv);
  }
}

extern "C" void kernel_launch(void* const* d_in, const int* in_sizes, int n_in,
                              void* d_out, int out_size, void* d_ws, size_t ws_size,
                              hipStream_t stream) {
  const float* q32 = (const float*)d_in[0];
  const float* k32 = (const float*)d_in[1];
  const float* v32 = (const float*)d_in[2];
  const float* Wq = (const float*)d_in[3]; const float* bq = (const float*)d_in[4];
  const float* Wk = (const float*)d_in[5]; const float* bk = (const float*)d_in[6];
  const float* Wv = (const float*)d_in[7]; const float* bv = (const float*)d_in[8];
  const float* Wo = (const float*)d_in[9]; const float* bo = (const float*)d_in[10];
  float* out = (float*)d_out;

  char* ws = (char*)d_ws;
  const size_t MB = 1u << 20;
  unsigned short* Xq  = (unsigned short*)(ws + 0 * MB);
  unsigned short* Xk  = (unsigned short*)(ws + 8 * MB);
  unsigned short* Xv  = (unsigned short*)(ws + 16 * MB);
  unsigned short* Wqt = (unsigned short*)(ws + 24 * MB);
  unsigned short* Wkt = (unsigned short*)(ws + 26 * MB);
  unsigned short* Wvt = (unsigned short*)(ws + 28 * MB);
  unsigned short* Wot = (unsigned short*)(ws + 30 * MB);
  unsigned short* Qb  = (unsigned short*)(ws + 32 * MB);
  unsigned short* Kb  = (unsigned short*)(ws + 40 * MB);
  unsigned short* Vtb = (unsigned short*)(ws + 48 * MB);
  unsigned short* AO  = Xq;  // safe: GEMM-Q (sole Xq reader) completes before attn writes

  const int n8 = (MROWS * EMBED) / 8;  // 524288
  cvt_f32_bf16<<<dim3(n8 / 256, 3), 256, 0, stream>>>(q32, k32, v32, Xq, Xk, Xv);
  wtrans<<<dim3(16, 16, 4), 256, 0, stream>>>(Wq, Wk, Wv, Wo, Wqt, Wkt, Wvt, Wot);

  const float qscale = 0.125f * 1.44269504088896340736f;  // (1/sqrt(64)) * log2(e)
  gemm_qkv<<<dim3(EMBED / 128, MROWS / 128, 3), 256, 0, stream>>>(
      Xq, Xk, Xv, Wqt, Wkt, Wvt, bq, bk, bv, Qb, Kb, Vtb, qscale);

  attn<<<dim3(SEQ / 64 * 32), 128, 0, stream>>>(Qb, Kb, Vtb, AO);

  gemm_out<<<dim3(EMBED / 64, MROWS / 128), 256, 0, stream>>>(AO, Wot, bo, out);
}

// Round 12
// 138.790 us; speedup vs baseline: 2.2699x; 1.0215x over previous
//
#include <hip/hip_runtime.h>
#include <hip/hip_bf16.h>

// Problem: B=2, S=2048, E=1024, H=16, D=64. All inputs fp32, output fp32.
// Pipeline: cvt X->bf16 | wtrans W->bf16 [N][K] | fused QKV GEMM (grid.z=3,
//           BN=128) -> Q(scaled log2e/8),K [BH][S][D], V^T [BH][D][S_perm]
//           | flash attention (32x32x16 MFMA, 2-wave blocks, 32q/wave,
//           gload_lds prefetch dbuf + 1 full-drain barrier/tile, in-lane
//           softmax + max3 tree, ONE shfl_xor(32)/tile, lane-local lrow
//           merged in epilogue, defer-max T13, P in-register, setprio T5)
//           | GEMM BN=64.
// LDS tiles: T2 XOR swizzle byte ^= ((row&7)<<4) within 128B rows; staged via
// global_load_lds with inverse-swizzled global source (linear LDS dest).
// History: r3 dbuf+counted-vmcnt raced -> full-drain barriers only.
//          r7 zero-staging attn latency-bound -> LDS staging mandatory.
//          r8 AF32 cvt-fusion regressed -> separate cvt pass.
//          r10 32x32 MFMA + in-lane P: attn 80->67us.
//          r11 permlane32_swap SELF-swap reduce FAILED (1.4e-2): semantics of
//          swap(x,x) != {own,partner} as paper-modeled -> reverted to
//          __shfl_xor merges (verified); kept deferred-lrow/max3/setprio.

#define EMBED 1024
#define NHEAD 16
#define HDIM 64
#define SEQ 2048
#define MROWS 4096  // B*S

typedef __attribute__((ext_vector_type(8))) __bf16 bf16x8;
typedef __attribute__((ext_vector_type(4))) float f32x4;
typedef __attribute__((ext_vector_type(16))) float f32x16;

__device__ __forceinline__ unsigned short f2bf(float f) {
  unsigned int u = __builtin_bit_cast(unsigned int, f);
  u += 0x7fffu + ((u >> 16) & 1u);  // round-to-nearest-even
  return (unsigned short)(u >> 16);
}

// packed f32x2 -> bf16x2 (T12 recipe; no builtin on gfx950)
__device__ __forceinline__ int cvtpk_bf16(float lo, float hi) {
  int r;
  asm("v_cvt_pk_bf16_f32 %0, %1, %2" : "=v"(r) : "v"(lo), "v"(hi));
  return r;
}

__device__ __forceinline__ float max3f(float a, float b, float c) {
  return fmaxf(fmaxf(a, b), c);  // clang fuses to v_max3_f32
}

// swizzled byte offset within a [rows][128B] LDS tile
__device__ __forceinline__ int swz(int row, int bcol) {
  return row * 128 + (bcol ^ ((row & 7) << 4));
}

// async global->LDS, 16B per lane. LDS dest = base + lane*16 (linear).
__device__ __forceinline__ void gload16(const void* g, void* l) {
  __builtin_amdgcn_global_load_lds((const __attribute__((address_space(1))) void*)g,
                                   (__attribute__((address_space(3))) void*)l, 16, 0, 0);
}

// ---- fp32 -> bf16, 8 elements/thread; blockIdx.y selects src/dst ----
__global__ __launch_bounds__(256) void cvt_f32_bf16(const float* __restrict__ i0, const float* __restrict__ i1,
                                                    const float* __restrict__ i2,
                                                    unsigned short* __restrict__ o0, unsigned short* __restrict__ o1,
                                                    unsigned short* __restrict__ o2) {
  const float* in; unsigned short* out;
  switch (blockIdx.y) {
    case 0: in = i0; out = o0; break;
    case 1: in = i1; out = o1; break;
    default: in = i2; out = o2; break;
  }
  int i = blockIdx.x * 256 + threadIdx.x;
  const float4* p = reinterpret_cast<const float4*>(in) + (size_t)i * 2;
  float4 a = p[0], b = p[1];
  int4 r;
  r.x = cvtpk_bf16(a.x, a.y);
  r.y = cvtpk_bf16(a.z, a.w);
  r.z = cvtpk_bf16(b.x, b.y);
  r.w = cvtpk_bf16(b.z, b.w);
  reinterpret_cast<int4*>(out)[i] = r;
}

// ---- W [K][N] fp32 -> Wt [N][K] bf16, 64x64 LDS tiles ----
__global__ __launch_bounds__(256) void wtrans(const float* __restrict__ w0, const float* __restrict__ w1,
                                              const float* __restrict__ w2, const float* __restrict__ w3,
                                              unsigned short* __restrict__ o0, unsigned short* __restrict__ o1,
                                              unsigned short* __restrict__ o2, unsigned short* __restrict__ o3) {
  __shared__ float tile[64][65];
  const float* src; unsigned short* dst;
  switch (blockIdx.z) {
    case 0: src = w0; dst = o0; break;
    case 1: src = w1; dst = o1; break;
    case 2: src = w2; dst = o2; break;
    default: src = w3; dst = o3; break;
  }
  const int k0 = blockIdx.y * 64, n0 = blockIdx.x * 64;
  const int c = threadIdx.x & 63, r0 = threadIdx.x >> 6;
#pragma unroll
  for (int i = 0; i < 16; ++i) {
    int r = r0 + i * 4;
    tile[r][c] = src[(size_t)(k0 + r) * EMBED + n0 + c];
  }
  __syncthreads();
#pragma unroll
  for (int i = 0; i < 16; ++i) {
    int nr = r0 + i * 4;
    dst[(size_t)(n0 + nr) * EMBED + k0 + c] = f2bf(tile[c][nr]);
  }
}

// ---- shared GEMM core: C[128 x BN tile] = A @ Bt^T + bias, then *oscale ----
// A bf16 [M][K]; Bt bf16 [N][K]. Staging via global_load_lds (m97 pattern).
// BN=128: waves 2x2, acc[4][4].  BN=64: waves 4x1, acc[2][4] (2 blocks/CU).
// mode 0: bf16 scatter to [B*H][S][D]; mode 1: fp32 row-major;
// mode 2: bf16 V^T scatter to [B*H][D][S] with seq-quartet bit-swap
//         (s-quartet q -> position-quartet ((q&1)<<1)|(q>>1)) so attn's PV
//         in-lane A-fragment permutation is compensated in V's layout.
template <int BN>
__device__ __forceinline__ void gemm_core(const unsigned short* __restrict__ A,
                                          const unsigned short* __restrict__ Bt,
                                          const float* __restrict__ bias,
                                          void* __restrict__ C, float oscale, int mode) {
  constexpr int K = EMBED;
  constexpr int MF = (BN == 128) ? 4 : 2;     // 16-row fragments per wave (M)
  constexpr int BRW = BN / 4;                 // B rows staged per wave
  __shared__ __align__(16) unsigned short Alds[128 * 64];
  __shared__ __align__(16) unsigned short Blds[BN * 64];
  char* Ab8 = (char*)Alds; char* Bb8 = (char*)Blds;
  const char* AB = (const char*)A;
  const char* BB = (const char*)Bt;
  const int tid = threadIdx.x;
  const int lane = tid & 63, w = tid >> 6;
  const int wr = (BN == 128) ? (w >> 1) : w;
  const int wc = (BN == 128) ? (w & 1) : 0;
  const int fr = lane & 15, fq = lane >> 4;
  const int m0 = blockIdx.y * 128, n0 = blockIdx.x * BN;
  const int bcol = (lane & 7) * 16;
  const int gsc = bcol ^ ((lane >> 3) << 4);  // row&7 == lane>>3 for all staged rows

  f32x4 acc[MF][4];
#pragma unroll
  for (int m = 0; m < MF; ++m)
#pragma unroll
    for (int n = 0; n < 4; ++n) acc[m][n] = f32x4{0.f, 0.f, 0.f, 0.f};

  for (int k0 = 0; k0 < K; k0 += 64) {
    __syncthreads();
#pragma unroll
    for (int i = 0; i < 4; ++i) {
      int row = w * 32 + i * 8 + (lane >> 3);
      gload16(AB + (size_t)(m0 + row) * (K * 2) + k0 * 2 + gsc, Ab8 + w * 4096 + i * 1024);
    }
#pragma unroll
    for (int i = 0; i < BRW / 8; ++i) {
      int row = w * BRW + i * 8 + (lane >> 3);
      gload16(BB + (size_t)(n0 + row) * (K * 2) + k0 * 2 + gsc, Bb8 + w * (BRW * 128) + i * 1024);
    }
    __syncthreads();  // drains vmcnt(0) -> tile staged
#pragma unroll
    for (int ks = 0; ks < 2; ++ks) {
      bf16x8 af[MF], bfr[4];
#pragma unroll
      for (int m = 0; m < MF; ++m) {
        int ar = wr * (MF * 16) + m * 16 + fr;
        af[m] = *reinterpret_cast<const bf16x8*>(Ab8 + swz(ar, ks * 64 + fq * 16));
      }
#pragma unroll
      for (int n = 0; n < 4; ++n) {
        int br = wc * 64 + n * 16 + fr;
        bfr[n] = *reinterpret_cast<const bf16x8*>(Bb8 + swz(br, ks * 64 + fq * 16));
      }
#pragma unroll
      for (int m = 0; m < MF; ++m)
#pragma unroll
        for (int n = 0; n < 4; ++n)
          acc[m][n] = __builtin_amdgcn_mfma_f32_16x16x32_bf16(af[m], bfr[n], acc[m][n], 0, 0, 0);
    }
  }

#pragma unroll
  for (int n = 0; n < 4; ++n) {
    int col = n0 + wc * 64 + n * 16 + fr;
    float bv = bias[col];
#pragma unroll
    for (int m = 0; m < MF; ++m) {
      int rowb = m0 + wr * (MF * 16) + m * 16 + fq * 4;
      if (mode == 2) {
        int b = rowb >> 11, s0 = rowb & (SEQ - 1);
        // seq-quartet bit-swap: quartet q -> ((q&1)<<1)|(q>>1) within each 16
        int s0p = (s0 & ~12) | ((s0 & 4) << 1) | ((s0 & 8) >> 1);
        int h = col >> 6, d = col & 63;
        int2 pk;
        pk.x = cvtpk_bf16((acc[m][n][0] + bv) * oscale, (acc[m][n][1] + bv) * oscale);
        pk.y = cvtpk_bf16((acc[m][n][2] + bv) * oscale, (acc[m][n][3] + bv) * oscale);
        *reinterpret_cast<int2*>(
            &reinterpret_cast<unsigned short*>(C)[((size_t)((b * NHEAD + h) * HDIM + d)) * SEQ + s0p]) = pk;
      } else if (mode == 0) {
#pragma unroll
        for (int r = 0; r < 4; ++r) {
          int row = rowb + r;
          float v = (acc[m][n][r] + bv) * oscale;
          int b = row >> 11, s = row & (SEQ - 1), h = col >> 6, d = col & 63;
          reinterpret_cast<unsigned short*>(C)[((size_t)((b * NHEAD + h) * SEQ + s) << 6) + d] = f2bf(v);
        }
      } else {
#pragma unroll
        for (int r = 0; r < 4; ++r)
          reinterpret_cast<float*>(C)[(size_t)(rowb + r) * EMBED + col] = acc[m][n][r] + bv;
      }
    }
  }
}

// fused QKV projection: blockIdx.z picks {Q, K, V}; 768 blocks = 3/CU.
__global__ __launch_bounds__(256) void gemm_qkv(
    const unsigned short* __restrict__ Xq, const unsigned short* __restrict__ Xk,
    const unsigned short* __restrict__ Xv,
    const unsigned short* __restrict__ Wqt, const unsigned short* __restrict__ Wkt,
    const unsigned short* __restrict__ Wvt,
    const float* __restrict__ bq, const float* __restrict__ bk, const float* __restrict__ bv,
    unsigned short* __restrict__ Qb, unsigned short* __restrict__ Kb,
    unsigned short* __restrict__ Vtb, float qscale) {
  switch (blockIdx.z) {
    case 0: gemm_core<128>(Xq, Wqt, bq, Qb, qscale, 0); break;
    case 1: gemm_core<128>(Xk, Wkt, bk, Kb, 1.0f, 0); break;
    default: gemm_core<128>(Xv, Wvt, bv, Vtb, 1.0f, 2); break;
  }
}

// output GEMM: 128x64 tiles -> 512 blocks = 2/CU (hide barrier drains)
__global__ __launch_bounds__(256) void gemm_out(const unsigned short* __restrict__ A,
                                                const unsigned short* __restrict__ Bt,
                                                const float* __restrict__ bias,
                                                float* __restrict__ C) {
  gemm_core<64>(A, Bt, bias, C, 1.0f, 1);
}

// ---- flash attention, 32x32x16 MFMA ----
// Q,K bf16 [B*H][S][D] (Q pre-scaled by log2e/8); Vt bf16 [B*H][D][S_perm].
// 2 waves x 32 q-rows per block. Lane: ql=lane&31 (q), t=lane>>5.
// QK: sc[kb] = mfma_32x32x16(Kfrag, Qfrag) -> C[k][q]: col q=ql, row
//   k=(reg&3)+8*(reg>>2)+4t within kb*32. [guide-verified C/D layout]
// Softmax in-lane (max3 tree); ONE __shfl_xor(32) per tile (max merge).
// lrow LANE-LOCAL per tile; single cross-half shfl merge in the epilogue.
// PV: A=P from own regs (V^T's bit-swapped seq layout compensates).
// Staging: r9-verified gload_lds prefetch dbuf + 1 full-drain barrier/tile.
__global__ __launch_bounds__(128) void attn(const unsigned short* __restrict__ Q,
                                            const unsigned short* __restrict__ Kk,
                                            const unsigned short* __restrict__ Vt,
                                            unsigned short* __restrict__ AO) {
  __shared__ __align__(16) unsigned short Klds[2][64 * 64];
  __shared__ __align__(16) unsigned short Vlds[2][64 * 64];  // [d][k_perm]
  const int tid = threadIdx.x, lane = tid & 63, w = tid >> 6;  // w in {0,1}
  const int ql = lane & 31, t = lane >> 5;

  // XCD swizzle: all 32 q-blocks of a head on one XCD (round-robin lin%8).
  const int lin = blockIdx.x;
  const int head = (lin & 7) * 4 + ((lin >> 3) & 3);
  const int q0 = (lin >> 5) * 64;
  const size_t hb = (size_t)head * SEQ * HDIM;
  const unsigned short* Qh = Q + hb;
  const char* KhB = (const char*)(Kk + hb);
  const char* VhB = (const char*)(Vt + hb);  // rows d, 4096B each

  // staging addressing (both-sides swizzle, rule #21)
  const int gsc = ((lane & 7) * 16) ^ ((lane >> 3) << 4);
  const int row0 = w * 32 + (lane >> 3);  // +i*8, i=0..3 -> 32 rows/wave

#define STAGE(kt_, b_)                                                                     \
  {                                                                                        \
    char* kb_ = (char*)Klds[b_];                                                           \
    char* vb_ = (char*)Vlds[b_];                                                           \
    _Pragma("unroll") for (int i_ = 0; i_ < 4; ++i_) {                                     \
      gload16(KhB + (size_t)((kt_)*64 + row0 + i_ * 8) * 128 + gsc,                        \
              kb_ + w * 4096 + i_ * 1024);                                                 \
      gload16(VhB + (size_t)(row0 + i_ * 8) * (SEQ * 2) + (kt_)*128 + gsc,                 \
              vb_ + w * 4096 + i_ * 1024);                                                 \
    }                                                                                      \
  }

  // Q fragments (B-operand): lane supplies Q[ql][d = s*16 + t*8 + e]
  bf16x8 qf[4];
  {
    const unsigned short* qp = Qh + (size_t)(q0 + w * 32 + ql) * HDIM + t * 8;
    qf[0] = *reinterpret_cast<const bf16x8*>(qp);
    qf[1] = *reinterpret_cast<const bf16x8*>(qp + 16);
    qf[2] = *reinterpret_cast<const bf16x8*>(qp + 32);
    qf[3] = *reinterpret_cast<const bf16x8*>(qp + 48);
  }
  f32x16 oacc0 = {}, oacc1 = {};  // d-blocks 0..31, 32..63
  float mrow = -1e30f, lrow = 0.f;  // lrow LANE-LOCAL (half-sum); merged at end

  STAGE(0, 0);
  __syncthreads();  // drains vmcnt(0) -> tile 0 staged

  for (int kt = 0; kt < SEQ / 64; ++kt) {
    const int cur = kt & 1;
    const bool more = (kt + 1 < SEQ / 64);
    if (more) STAGE(kt + 1, cur ^ 1);  // async prefetch; drained by tile-end barrier
    char* Kb8 = (char*)Klds[cur];
    char* Vb8 = (char*)Vlds[cur];

    // S^T = K.Q^T (log2 domain): sc0 = keys kb=0 (k 0..31), sc1 = kb=1
    f32x16 sc0 = {}, sc1 = {};
    __builtin_amdgcn_s_setprio(1);
#pragma unroll
    for (int s = 0; s < 4; ++s) {
      bf16x8 kf0 = *reinterpret_cast<const bf16x8*>(Kb8 + swz(ql, s * 32 + t * 16));
      bf16x8 kf1 = *reinterpret_cast<const bf16x8*>(Kb8 + swz(32 + ql, s * 32 + t * 16));
      sc0 = __builtin_amdgcn_mfma_f32_32x32x16_bf16(kf0, qf[s], sc0, 0, 0, 0);
      sc1 = __builtin_amdgcn_mfma_f32_32x32x16_bf16(kf1, qf[s], sc1, 0, 0, 0);
    }
    __builtin_amdgcn_s_setprio(0);

    // in-lane max over 32 scores (max3 tree), cross-half via verified shfl_xor
    float l1[12];
#pragma unroll
    for (int i = 0; i < 5; ++i) l1[i] = max3f(sc0[3 * i], sc0[3 * i + 1], sc0[3 * i + 2]);
#pragma unroll
    for (int i = 0; i < 5; ++i) l1[5 + i] = max3f(sc1[3 * i], sc1[3 * i + 1], sc1[3 * i + 2]);
    l1[10] = sc0[15];
    l1[11] = sc1[15];
    float l2a = max3f(l1[0], l1[1], l1[2]);
    float l2b = max3f(l1[3], l1[4], l1[5]);
    float l2c = max3f(l1[6], l1[7], l1[8]);
    float l2d = max3f(l1[9], l1[10], l1[11]);
    float mt = fmaxf(max3f(l2a, l2b, l2c), l2d);
    mt = fmaxf(mt, __shfl_xor(mt, 32));

    // T13 defer-max: only rescale when some row's max grew past 2^8 headroom
    if (!__all(mt <= mrow + 8.0f)) {
      float mn = fmaxf(mrow, mt);
      float resc = __builtin_amdgcn_exp2f(mrow - mn);
      lrow *= resc;
#pragma unroll
      for (int r = 0; r < 16; ++r) {
        float rq = __shfl(resc, (r & 3) + 8 * (r >> 2) + 4 * t, 64);
        oacc0[r] *= rq;
        oacc1[r] *= rq;
      }
      mrow = mn;
    }

    // P = exp2(S - mrow) in place; lane-local partial sums (no per-tile merge)
    float ps0 = 0.f, ps1 = 0.f, ps2 = 0.f, ps3 = 0.f;
#pragma unroll
    for (int i = 0; i < 4; ++i) {
      sc0[4 * i + 0] = __builtin_amdgcn_exp2f(sc0[4 * i + 0] - mrow);
      sc0[4 * i + 1] = __builtin_amdgcn_exp2f(sc0[4 * i + 1] - mrow);
      sc0[4 * i + 2] = __builtin_amdgcn_exp2f(sc0[4 * i + 2] - mrow);
      sc0[4 * i + 3] = __builtin_amdgcn_exp2f(sc0[4 * i + 3] - mrow);
      sc1[4 * i + 0] = __builtin_amdgcn_exp2f(sc1[4 * i + 0] - mrow);
      sc1[4 * i + 1] = __builtin_amdgcn_exp2f(sc1[4 * i + 1] - mrow);
      sc1[4 * i + 2] = __builtin_amdgcn_exp2f(sc1[4 * i + 2] - mrow);
      sc1[4 * i + 3] = __builtin_amdgcn_exp2f(sc1[4 * i + 3] - mrow);
      ps0 += sc0[4 * i + 0] + sc0[4 * i + 1];
      ps1 += sc0[4 * i + 2] + sc0[4 * i + 3];
      ps2 += sc1[4 * i + 0] + sc1[4 * i + 1];
      ps3 += sc1[4 * i + 2] + sc1[4 * i + 3];
    }
    lrow += (ps0 + ps1) + (ps2 + ps3);

    // PA fragments: pa[s] = own regs 8*(s&1)..+7 of sc[s>>1] (no cross-lane;
    // slot->k quartet permutation is baked into V^T's global layout)
    int4 paw[4];
#pragma unroll
    for (int s2 = 0; s2 < 2; ++s2) {
      paw[s2].x     = cvtpk_bf16(sc0[8 * s2 + 0], sc0[8 * s2 + 1]);
      paw[s2].y     = cvtpk_bf16(sc0[8 * s2 + 2], sc0[8 * s2 + 3]);
      paw[s2].z     = cvtpk_bf16(sc0[8 * s2 + 4], sc0[8 * s2 + 5]);
      paw[s2].w     = cvtpk_bf16(sc0[8 * s2 + 6], sc0[8 * s2 + 7]);
      paw[2 + s2].x = cvtpk_bf16(sc1[8 * s2 + 0], sc1[8 * s2 + 1]);
      paw[2 + s2].y = cvtpk_bf16(sc1[8 * s2 + 2], sc1[8 * s2 + 3]);
      paw[2 + s2].z = cvtpk_bf16(sc1[8 * s2 + 4], sc1[8 * s2 + 5]);
      paw[2 + s2].w = cvtpk_bf16(sc1[8 * s2 + 6], sc1[8 * s2 + 7]);
    }

    // PV: O[q][d] += P.V; V-fragment (B-operand) rows d, positions s*16+slot
    __builtin_amdgcn_s_setprio(1);
#pragma unroll
    for (int s = 0; s < 4; ++s) {
      bf16x8 pa = __builtin_bit_cast(bf16x8, paw[s]);
      bf16x8 v0 = *reinterpret_cast<const bf16x8*>(Vb8 + swz(ql, s * 32 + t * 16));
      bf16x8 v1 = *reinterpret_cast<const bf16x8*>(Vb8 + swz(32 + ql, s * 32 + t * 16));
      oacc0 = __builtin_amdgcn_mfma_f32_32x32x16_bf16(pa, v0, oacc0, 0, 0, 0);
      oacc1 = __builtin_amdgcn_mfma_f32_32x32x16_bf16(pa, v1, oacc1, 0, 0, 0);
    }
    __builtin_amdgcn_s_setprio(0);

    __syncthreads();  // all waves done reading cur + prefetch drained (vmcnt 0)
  }
#undef STAGE

  // merge the two half-sums of lrow once (was 32 per-tile shuffles)
  lrow += __shfl_xor(lrow, 32);

  const int b = head >> 4, hh = head & 15;
#pragma unroll
  for (int r = 0; r < 16; ++r) {
    int qr = (r & 3) + 8 * (r >> 2) + 4 * t;
    float inv = 1.0f / __shfl(lrow, qr, 64);
    int srow = q0 + w * 32 + qr;
    size_t ob = (size_t)(b * SEQ + srow) * EMBED + hh * 64 + ql;
    AO[ob] = f2bf(oacc0[r] * inv);
    AO[ob + 32] = f2bf(oacc1[r] * inv);
  }
}

extern "C" void kernel_launch(void* const* d_in, const int* in_sizes, int n_in,
                              void* d_out, int out_size, void* d_ws, size_t ws_size,
                              hipStream_t stream) {
  const float* q32 = (const float*)d_in[0];
  const float* k32 = (const float*)d_in[1];
  const float* v32 = (const float*)d_in[2];
  const float* Wq = (const float*)d_in[3]; const float* bq = (const float*)d_in[4];
  const float* Wk = (const float*)d_in[5]; const float* bk = (const float*)d_in[6];
  const float* Wv = (const float*)d_in[7]; const float* bv = (const float*)d_in[8];
  const float* Wo = (const float*)d_in[9]; const float* bo = (const float*)d_in[10];
  float* out = (float*)d_out;

  char* ws = (char*)d_ws;
  const size_t MB = 1u << 20;
  unsigned short* Xq  = (unsigned short*)(ws + 0 * MB);
  unsigned short* Xk  = (unsigned short*)(ws + 8 * MB);
  unsigned short* Xv  = (unsigned short*)(ws + 16 * MB);
  unsigned short* Wqt = (unsigned short*)(ws + 24 * MB);
  unsigned short* Wkt = (unsigned short*)(ws + 26 * MB);
  unsigned short* Wvt = (unsigned short*)(ws + 28 * MB);
  unsigned short* Wot = (unsigned short*)(ws + 30 * MB);
  unsigned short* Qb  = (unsigned short*)(ws + 32 * MB);
  unsigned short* Kb  = (unsigned short*)(ws + 40 * MB);
  unsigned short* Vtb = (unsigned short*)(ws + 48 * MB);
  unsigned short* AO  = Xq;  // safe: GEMM-Q (sole Xq reader) completes before attn writes

  const int n8 = (MROWS * EMBED) / 8;  // 524288
  cvt_f32_bf16<<<dim3(n8 / 256, 3), 256, 0, stream>>>(q32, k32, v32, Xq, Xk, Xv);
  wtrans<<<dim3(16, 16, 4), 256, 0, stream>>>(Wq, Wk, Wv, Wo, Wqt, Wkt, Wvt, Wot);

  const float qscale = 0.125f * 1.44269504088896340736f;  // (1/sqrt(64)) * log2(e)
  gemm_qkv<<<dim3(EMBED / 128, MROWS / 128, 3), 256, 0, stream>>>(
      Xq, Xk, Xv, Wqt, Wkt, Wvt, bq, bk, bv, Qb, Kb, Vtb, qscale);

  attn<<<dim3(SEQ / 64 * 32), 128, 0, stream>>>(Qb, Kb, Vtb, AO);

  gemm_out<<<dim3(EMBED / 64, MROWS / 128), 256, 0, stream>>>(AO, Wot, bo, out);
}